// Round 1
// baseline (7351.228 us; speedup 1.0000x reference)
//
#include <hip/hip_runtime.h>

constexpr int R_ = 5, H_ = 8, D_ = 16, C_ = 128;
constexpr int RH = R_ * H_;   // 40 softmax slots

// ---- monotone int encoding of float for atomicMax ----
__device__ __forceinline__ int enc_f(float f) {
    int i = __float_as_int(f);
    return i >= 0 ? i : (i ^ 0x7FFFFFFF);
}
__device__ __forceinline__ float dec_f(int i) {
    int j = i >= 0 ? i : (i ^ 0x7FFFFFFF);
    return __int_as_float(j);
}

// ---- init: m = -inf (encoded), s = 0, alpha = softmax(semantic_att, axis=0) ----
__global__ void init_kernel(const float* __restrict__ sa, int* __restrict__ m_enc,
                            float* __restrict__ s, float* __restrict__ alpha) {
    int t = threadIdx.x;
    if (t < RH) { m_enc[t] = (int)0x80000000; s[t] = 0.0f; }
    if (t < D_) {
        float vals[H_];
        float mx = -1e30f;
        #pragma unroll
        for (int h = 0; h < H_; ++h) { vals[h] = sa[h * D_ + t]; mx = fmaxf(mx, vals[h]); }
        float sum = 0.0f;
        #pragma unroll
        for (int h = 0; h < H_; ++h) { vals[h] = expf(vals[h] - mx); sum += vals[h]; }
        float inv = 1.0f / sum;
        #pragma unroll
        for (int h = 0; h < H_; ++h) alpha[h * D_ + t] = vals[h] * inv;
    }
}

// ---- shared GEMM micro-kernel: out[row0.., :] = xs(64x128) @ W^T + b ----
__device__ __forceinline__ void tile_gemm_store(const float* __restrict__ xs,
                                                const float* __restrict__ W,
                                                const float* __restrict__ b,
                                                float* __restrict__ out,
                                                int row0, int N) {
    int tid = threadIdx.x;
    int c0 = (tid & 31) * 4;   // 4 output cols
    int r0 = (tid >> 5) * 8;   // 8 rows
    float acc[8][4];
    float b0 = b[c0], b1 = b[c0 + 1], b2 = b[c0 + 2], b3 = b[c0 + 3];
    #pragma unroll
    for (int r = 0; r < 8; ++r) { acc[r][0] = b0; acc[r][1] = b1; acc[r][2] = b2; acc[r][3] = b3; }
    for (int kk = 0; kk < 128; kk += 4) {
        float4 w0 = *(const float4*)(W + (c0 + 0) * C_ + kk);
        float4 w1 = *(const float4*)(W + (c0 + 1) * C_ + kk);
        float4 w2 = *(const float4*)(W + (c0 + 2) * C_ + kk);
        float4 w3 = *(const float4*)(W + (c0 + 3) * C_ + kk);
        #pragma unroll
        for (int r = 0; r < 8; ++r) {
            float4 xv = *(const float4*)(xs + (r0 + r) * C_ + kk);
            acc[r][0] += xv.x * w0.x + xv.y * w0.y + xv.z * w0.z + xv.w * w0.w;
            acc[r][1] += xv.x * w1.x + xv.y * w1.y + xv.z * w1.z + xv.w * w1.w;
            acc[r][2] += xv.x * w2.x + xv.y * w2.y + xv.z * w2.z + xv.w * w2.w;
            acc[r][3] += xv.x * w3.x + xv.y * w3.y + xv.z * w3.z + xv.w * w3.w;
        }
    }
    #pragma unroll
    for (int r = 0; r < 8; ++r) {
        int grow = row0 + r0 + r;
        if (grow < N) {
            float4 o = make_float4(acc[r][0], acc[r][1], acc[r][2], acc[r][3]);
            *(float4*)(out + (size_t)grow * C_ + c0) = o;
        }
    }
}

// ---- fused q/k/v GEMM: x tile staged once, reused for 3 weight matrices ----
__global__ __launch_bounds__(256) void qkv_kernel(const float* __restrict__ x,
                                                  const float* __restrict__ Wq, const float* __restrict__ bq,
                                                  const float* __restrict__ Wk, const float* __restrict__ bk,
                                                  const float* __restrict__ Wv, const float* __restrict__ bv,
                                                  float* __restrict__ q, float* __restrict__ k,
                                                  float* __restrict__ v, int N) {
    __shared__ float xs[64 * 128];
    int row0 = blockIdx.x * 64;
    int tid = threadIdx.x;
    #pragma unroll
    for (int j = 0; j < 8; ++j) {
        int f = tid + j * 256;       // float4 index within tile (2048 total)
        int r = f >> 5, c4 = f & 31;
        int grow = row0 + r;
        float4 val = make_float4(0.f, 0.f, 0.f, 0.f);
        if (grow < N) val = *(const float4*)(x + (size_t)grow * C_ + c4 * 4);
        *(float4*)(xs + r * C_ + c4 * 4) = val;
    }
    __syncthreads();
    tile_gemm_store(xs, Wq, bq, q, row0, N);
    tile_gemm_store(xs, Wk, bk, k, row0, N);
    tile_gemm_store(xs, Wv, bv, v, row0, N);
}

// ---- per-(edge,head) scores + segment max over (relation, head) ----
__global__ __launch_bounds__(256) void scores_kernel(const float* __restrict__ q,
                                                     const float* __restrict__ k,
                                                     const int* __restrict__ ei,
                                                     const int* __restrict__ et,
                                                     float* __restrict__ scores,
                                                     int* __restrict__ m_enc, int E) {
    __shared__ int lmax[RH];
    int tid = threadIdx.x;
    if (tid < RH) lmax[tid] = (int)0x80000000;
    __syncthreads();
    int i = blockIdx.x * 256 + tid;
    if (i < E * H_) {
        int e = i >> 3, h = i & 7;
        int r = ei[e], c = ei[E + e], t = et[e];
        const float4* qp = (const float4*)(q + (size_t)r * C_ + h * D_);
        const float4* kp = (const float4*)(k + (size_t)c * C_ + h * D_);
        float acc = 0.f;
        #pragma unroll
        for (int j = 0; j < 4; ++j) {
            float4 a = qp[j], b = kp[j];
            acc += a.x * b.x + a.y * b.y + a.z * b.z + a.w * b.w;
        }
        acc *= 0.25f;                 // 1/sqrt(16)
        scores[i] = acc;
        atomicMax(&lmax[t * H_ + h], enc_f(acc));
    }
    __syncthreads();
    if (tid < RH && lmax[tid] != (int)0x80000000) atomicMax(&m_enc[tid], lmax[tid]);
}

// ---- e = exp(score - m), segment sum ----
__global__ __launch_bounds__(256) void expsum_kernel(float* __restrict__ scores,
                                                     const int* __restrict__ et,
                                                     const int* __restrict__ m_enc,
                                                     float* __restrict__ s, int E) {
    __shared__ float lsum[RH];
    __shared__ float lm[RH];
    int tid = threadIdx.x;
    if (tid < RH) { lsum[tid] = 0.f; lm[tid] = dec_f(m_enc[tid]); }
    __syncthreads();
    int i = blockIdx.x * 256 + tid;
    if (i < E * H_) {
        int e = i >> 3, h = i & 7, t = et[e];
        float val = expf(scores[i] - lm[t * H_ + h]);
        scores[i] = val;
        atomicAdd(&lsum[t * H_ + h], val);
    }
    __syncthreads();
    if (tid < RH && lsum[tid] != 0.f) atomicAdd(&s[tid], lsum[tid]);
}

// ---- attn = e/s; scatter-add attn * v[col] into outacc[row] ----
__global__ __launch_bounds__(256) void scatter_kernel(const float* __restrict__ scores,
                                                      const float* __restrict__ v,
                                                      const int* __restrict__ ei,
                                                      const int* __restrict__ et,
                                                      const float* __restrict__ s,
                                                      float* __restrict__ outacc, int E) {
    __shared__ float sinv[RH];
    int tid = threadIdx.x;
    if (tid < RH) { float sv = s[tid]; sinv[tid] = sv > 0.f ? 1.f / sv : 0.f; }
    __syncthreads();
    int i = blockIdx.x * 256 + tid;
    if (i >= E * H_) return;
    int e = i >> 3, h = i & 7, t = et[e];
    float a = scores[i] * sinv[t * H_ + h];
    int r = ei[e], c = ei[E + e];
    const float4* vp = (const float4*)(v + (size_t)c * C_ + h * D_);
    float* op = outacc + (size_t)r * C_ + h * D_;
    #pragma unroll
    for (int j = 0; j < 4; ++j) {
        float4 mv = vp[j];
        atomicAdd(op + j * 4 + 0, mv.x * a);
        atomicAdd(op + j * 4 + 1, mv.y * a);
        atomicAdd(op + j * 4 + 2, mv.z * a);
        atomicAdd(op + j * 4 + 3, mv.w * a);
    }
}

// ---- final GEMM: out = (outacc * alpha) @ Wo^T + bo ----
__global__ __launch_bounds__(256) void ogemm_kernel(const float* __restrict__ outacc,
                                                    const float* __restrict__ alpha,
                                                    const float* __restrict__ Wo,
                                                    const float* __restrict__ bo,
                                                    float* __restrict__ out, int N) {
    __shared__ float xs[64 * 128];
    int row0 = blockIdx.x * 64;
    int tid = threadIdx.x;
    #pragma unroll
    for (int j = 0; j < 8; ++j) {
        int f = tid + j * 256;
        int r = f >> 5, c4 = f & 31;
        int grow = row0 + r;
        float4 val = make_float4(0.f, 0.f, 0.f, 0.f);
        if (grow < N) {
            val = *(const float4*)(outacc + (size_t)grow * C_ + c4 * 4);
            float4 al = *(const float4*)(alpha + c4 * 4);
            val.x *= al.x; val.y *= al.y; val.z *= al.z; val.w *= al.w;
        }
        *(float4*)(xs + r * C_ + c4 * 4) = val;
    }
    __syncthreads();
    tile_gemm_store(xs, Wo, bo, out, row0, N);
}

extern "C" void kernel_launch(void* const* d_in, const int* in_sizes, int n_in,
                              void* d_out, int out_size, void* d_ws, size_t ws_size,
                              hipStream_t stream) {
    const float* x  = (const float*)d_in[0];
    const int*   ei = (const int*)d_in[1];
    const int*   et = (const int*)d_in[2];
    // d_in[3] = num_relations (scalar) — R_ hardcoded to 5 per problem setup
    const float* Wq = (const float*)d_in[4];
    const float* bq = (const float*)d_in[5];
    const float* Wk = (const float*)d_in[6];
    const float* bk = (const float*)d_in[7];
    const float* Wv = (const float*)d_in[8];
    const float* bv = (const float*)d_in[9];
    const float* sa = (const float*)d_in[10];
    const float* Wo = (const float*)d_in[11];
    const float* bo = (const float*)d_in[12];
    float* out = (float*)d_out;

    int N = in_sizes[0] / C_;
    int E = in_sizes[2];

    float* ws = (float*)d_ws;
    float* q      = ws;
    float* k      = q + (size_t)N * C_;
    float* v      = k + (size_t)N * C_;
    float* outacc = v + (size_t)N * C_;
    float* scores = outacc + (size_t)N * C_;
    int*   m_enc  = (int*)(scores + (size_t)E * H_);
    float* s      = (float*)(m_enc + RH);
    float* alpha  = s + RH;
    size_t need = (size_t)((char*)(alpha + C_) - (char*)d_ws);
    if (ws_size < need) return;   // workspace too small — fail cleanly

    hipMemsetAsync(outacc, 0, (size_t)N * C_ * sizeof(float), stream);
    init_kernel<<<1, 64, 0, stream>>>(sa, m_enc, s, alpha);
    qkv_kernel<<<(N + 63) / 64, 256, 0, stream>>>(x, Wq, bq, Wk, bk, Wv, bv, q, k, v, N);
    int nb = (E * H_ + 255) / 256;
    scores_kernel<<<nb, 256, 0, stream>>>(q, k, ei, et, scores, m_enc, E);
    expsum_kernel<<<nb, 256, 0, stream>>>(scores, et, m_enc, s, E);
    scatter_kernel<<<nb, 256, 0, stream>>>(scores, v, ei, et, s, outacc, E);
    ogemm_kernel<<<(N + 63) / 64, 256, 0, stream>>>(outacc, alpha, Wo, bo, out, N);
}

// Round 2
// 1928.364 us; speedup vs baseline: 3.8122x; 3.8122x over previous
//
#include <hip/hip_runtime.h>

constexpr int R_ = 5, H_ = 8, D_ = 16, C_ = 128;
constexpr int RH = R_ * H_;   // 40 softmax slots

// ---- monotone int encoding of float for atomicMax ----
__device__ __forceinline__ int enc_f(float f) {
    int i = __float_as_int(f);
    return i >= 0 ? i : (i ^ 0x7FFFFFFF);
}
__device__ __forceinline__ float dec_f(int i) {
    int j = i >= 0 ? i : (i ^ 0x7FFFFFFF);
    return __int_as_float(j);
}

// ---- init: m = -inf (encoded), s = 0, alpha = softmax(semantic_att, axis=0) ----
__global__ void init_kernel(const float* __restrict__ sa, int* __restrict__ m_enc,
                            float* __restrict__ s, float* __restrict__ alpha) {
    int t = threadIdx.x;
    if (t < RH) { m_enc[t] = (int)0x80000000; s[t] = 0.0f; }
    if (t < D_) {
        float vals[H_];
        float mx = -1e30f;
        #pragma unroll
        for (int h = 0; h < H_; ++h) { vals[h] = sa[h * D_ + t]; mx = fmaxf(mx, vals[h]); }
        float sum = 0.0f;
        #pragma unroll
        for (int h = 0; h < H_; ++h) { vals[h] = expf(vals[h] - mx); sum += vals[h]; }
        float inv = 1.0f / sum;
        #pragma unroll
        for (int h = 0; h < H_; ++h) alpha[h * D_ + t] = vals[h] * inv;
    }
}

// ---- CSR build: histogram of destination rows ----
__global__ __launch_bounds__(256) void hist_kernel(const int* __restrict__ ei,
                                                   int* __restrict__ cnt, int E) {
    int i = blockIdx.x * 256 + threadIdx.x;
    if (i < E) atomicAdd(&cnt[ei[i]], 1);
}

// ---- CSR build: exclusive scan over N counts (single block) ----
__global__ __launch_bounds__(1024) void scan_kernel(int* __restrict__ cnt,
                                                    int* __restrict__ offs, int N) {
    __shared__ int tot[1024];
    int t = threadIdx.x;
    int chunk = (N + 1023) >> 10;
    int beg = t * chunk;
    int end = min(beg + chunk, N);
    int sum = 0;
    for (int i = beg; i < end; ++i) sum += cnt[i];
    tot[t] = sum;
    __syncthreads();
    for (int d = 1; d < 1024; d <<= 1) {
        int val = (t >= d) ? tot[t - d] : 0;
        __syncthreads();
        tot[t] += val;
        __syncthreads();
    }
    int base = (t == 0) ? 0 : tot[t - 1];
    for (int i = beg; i < end; ++i) {
        int c = cnt[i];
        offs[i] = base;
        cnt[i] = base;    // cursor init for fill pass
        base += c;
    }
    if (t == 1023) offs[N] = base;
}

// ---- CSR build: scatter edge ids into row-sorted order ----
__global__ __launch_bounds__(256) void fill_kernel(const int* __restrict__ ei,
                                                   int* __restrict__ cursor,
                                                   int* __restrict__ sorted, int E) {
    int i = blockIdx.x * 256 + threadIdx.x;
    if (i < E) {
        int pos = atomicAdd(&cursor[ei[i]], 1);
        sorted[pos] = i;
    }
}

// ---- shared GEMM micro-kernel: out[row0.., :] = xs(64x128) @ W^T + b ----
__device__ __forceinline__ void tile_gemm_store(const float* __restrict__ xs,
                                                const float* __restrict__ W,
                                                const float* __restrict__ b,
                                                float* __restrict__ out,
                                                int row0, int N) {
    int tid = threadIdx.x;
    int c0 = (tid & 31) * 4;   // 4 output cols
    int r0 = (tid >> 5) * 8;   // 8 rows
    float acc[8][4];
    float b0 = b[c0], b1 = b[c0 + 1], b2 = b[c0 + 2], b3 = b[c0 + 3];
    #pragma unroll
    for (int r = 0; r < 8; ++r) { acc[r][0] = b0; acc[r][1] = b1; acc[r][2] = b2; acc[r][3] = b3; }
    for (int kk = 0; kk < 128; kk += 4) {
        float4 w0 = *(const float4*)(W + (c0 + 0) * C_ + kk);
        float4 w1 = *(const float4*)(W + (c0 + 1) * C_ + kk);
        float4 w2 = *(const float4*)(W + (c0 + 2) * C_ + kk);
        float4 w3 = *(const float4*)(W + (c0 + 3) * C_ + kk);
        #pragma unroll
        for (int r = 0; r < 8; ++r) {
            float4 xv = *(const float4*)(xs + (r0 + r) * C_ + kk);
            acc[r][0] += xv.x * w0.x + xv.y * w0.y + xv.z * w0.z + xv.w * w0.w;
            acc[r][1] += xv.x * w1.x + xv.y * w1.y + xv.z * w1.z + xv.w * w1.w;
            acc[r][2] += xv.x * w2.x + xv.y * w2.y + xv.z * w2.z + xv.w * w2.w;
            acc[r][3] += xv.x * w3.x + xv.y * w3.y + xv.z * w3.z + xv.w * w3.w;
        }
    }
    #pragma unroll
    for (int r = 0; r < 8; ++r) {
        int grow = row0 + r0 + r;
        if (grow < N) {
            float4 o = make_float4(acc[r][0], acc[r][1], acc[r][2], acc[r][3]);
            *(float4*)(out + (size_t)grow * C_ + c0) = o;
        }
    }
}

// ---- fused q/k/v GEMM: x tile staged once, reused for 3 weight matrices ----
__global__ __launch_bounds__(256) void qkv_kernel(const float* __restrict__ x,
                                                  const float* __restrict__ Wq, const float* __restrict__ bq,
                                                  const float* __restrict__ Wk, const float* __restrict__ bk,
                                                  const float* __restrict__ Wv, const float* __restrict__ bv,
                                                  float* __restrict__ q, float* __restrict__ k,
                                                  float* __restrict__ v, int N) {
    __shared__ float xs[64 * 128];
    int row0 = blockIdx.x * 64;
    int tid = threadIdx.x;
    #pragma unroll
    for (int j = 0; j < 8; ++j) {
        int f = tid + j * 256;       // float4 index within tile (2048 total)
        int r = f >> 5, c4 = f & 31;
        int grow = row0 + r;
        float4 val = make_float4(0.f, 0.f, 0.f, 0.f);
        if (grow < N) val = *(const float4*)(x + (size_t)grow * C_ + c4 * 4);
        *(float4*)(xs + r * C_ + c4 * 4) = val;
    }
    __syncthreads();
    tile_gemm_store(xs, Wq, bq, q, row0, N);
    tile_gemm_store(xs, Wk, bk, k, row0, N);
    tile_gemm_store(xs, Wv, bv, v, row0, N);
}

// ---- per-(edge,head) scores + segment max over (relation, head) ----
__global__ __launch_bounds__(256) void scores_kernel(const float* __restrict__ q,
                                                     const float* __restrict__ k,
                                                     const int* __restrict__ ei,
                                                     const int* __restrict__ et,
                                                     float* __restrict__ scores,
                                                     int* __restrict__ m_enc, int E) {
    __shared__ int lmax[RH];
    int tid = threadIdx.x;
    if (tid < RH) lmax[tid] = (int)0x80000000;
    __syncthreads();
    int i = blockIdx.x * 256 + tid;
    if (i < E * H_) {
        int e = i >> 3, h = i & 7;
        int r = ei[e], c = ei[E + e], t = et[e];
        const float4* qp = (const float4*)(q + (size_t)r * C_ + h * D_);
        const float4* kp = (const float4*)(k + (size_t)c * C_ + h * D_);
        float acc = 0.f;
        #pragma unroll
        for (int j = 0; j < 4; ++j) {
            float4 a = qp[j], b = kp[j];
            acc += a.x * b.x + a.y * b.y + a.z * b.z + a.w * b.w;
        }
        acc *= 0.25f;                 // 1/sqrt(16)
        scores[i] = acc;
        atomicMax(&lmax[t * H_ + h], enc_f(acc));
    }
    __syncthreads();
    if (tid < RH && lmax[tid] != (int)0x80000000) atomicMax(&m_enc[tid], lmax[tid]);
}

// ---- e = exp(score - m), segment sum ----
__global__ __launch_bounds__(256) void expsum_kernel(float* __restrict__ scores,
                                                     const int* __restrict__ et,
                                                     const int* __restrict__ m_enc,
                                                     float* __restrict__ s, int E) {
    __shared__ float lsum[RH];
    __shared__ float lm[RH];
    int tid = threadIdx.x;
    if (tid < RH) { lsum[tid] = 0.f; lm[tid] = dec_f(m_enc[tid]); }
    __syncthreads();
    int i = blockIdx.x * 256 + tid;
    if (i < E * H_) {
        int e = i >> 3, h = i & 7, t = et[e];
        float val = expf(scores[i] - lm[t * H_ + h]);
        scores[i] = val;
        atomicAdd(&lsum[t * H_ + h], val);
    }
    __syncthreads();
    if (tid < RH && lsum[tid] != 0.f) atomicAdd(&s[tid], lsum[tid]);
}

// ---- gather: out[row] = sum over incoming edges of attn * v[col], no atomics ----
__global__ __launch_bounds__(64) void gather_kernel(const float* __restrict__ scores,
                                                    const float* __restrict__ v,
                                                    const int* __restrict__ ei,
                                                    const int* __restrict__ et,
                                                    const float* __restrict__ s,
                                                    const int* __restrict__ offs,
                                                    const int* __restrict__ sorted,
                                                    float* __restrict__ outacc, int E) {
    __shared__ float sinv[RH];
    int tid = threadIdx.x;
    if (tid < RH) { float sv = s[tid]; sinv[tid] = sv > 0.f ? 1.f / sv : 0.f; }
    __syncthreads();
    int row = blockIdx.x;
    int beg = offs[row], end = offs[row + 1];
    int c0 = tid * 2;            // two output channels per lane
    int h = c0 >> 4;             // head for both channels
    float ax = 0.f, ay = 0.f;
    int j = beg;
    for (; j + 1 < end; j += 2) {
        int e0 = sorted[j], e1 = sorted[j + 1];
        int col0 = ei[E + e0], col1 = ei[E + e1];
        int t0 = et[e0], t1 = et[e1];
        float a0 = scores[e0 * H_ + h] * sinv[t0 * H_ + h];
        float a1 = scores[e1 * H_ + h] * sinv[t1 * H_ + h];
        float2 m0 = *(const float2*)(v + (size_t)col0 * C_ + c0);
        float2 m1 = *(const float2*)(v + (size_t)col1 * C_ + c0);
        ax += m0.x * a0 + m1.x * a1;
        ay += m0.y * a0 + m1.y * a1;
    }
    if (j < end) {
        int e0 = sorted[j];
        int col0 = ei[E + e0];
        int t0 = et[e0];
        float a0 = scores[e0 * H_ + h] * sinv[t0 * H_ + h];
        float2 m0 = *(const float2*)(v + (size_t)col0 * C_ + c0);
        ax += m0.x * a0;
        ay += m0.y * a0;
    }
    *(float2*)(outacc + (size_t)row * C_ + c0) = make_float2(ax, ay);
}

// ---- final GEMM: out = (outacc * alpha) @ Wo^T + bo ----
__global__ __launch_bounds__(256) void ogemm_kernel(const float* __restrict__ outacc,
                                                    const float* __restrict__ alpha,
                                                    const float* __restrict__ Wo,
                                                    const float* __restrict__ bo,
                                                    float* __restrict__ out, int N) {
    __shared__ float xs[64 * 128];
    int row0 = blockIdx.x * 64;
    int tid = threadIdx.x;
    #pragma unroll
    for (int j = 0; j < 8; ++j) {
        int f = tid + j * 256;
        int r = f >> 5, c4 = f & 31;
        int grow = row0 + r;
        float4 val = make_float4(0.f, 0.f, 0.f, 0.f);
        if (grow < N) {
            val = *(const float4*)(outacc + (size_t)grow * C_ + c4 * 4);
            float4 al = *(const float4*)(alpha + c4 * 4);
            val.x *= al.x; val.y *= al.y; val.z *= al.z; val.w *= al.w;
        }
        *(float4*)(xs + r * C_ + c4 * 4) = val;
    }
    __syncthreads();
    tile_gemm_store(xs, Wo, bo, out, row0, N);
}

extern "C" void kernel_launch(void* const* d_in, const int* in_sizes, int n_in,
                              void* d_out, int out_size, void* d_ws, size_t ws_size,
                              hipStream_t stream) {
    const float* x  = (const float*)d_in[0];
    const int*   ei = (const int*)d_in[1];
    const int*   et = (const int*)d_in[2];
    // d_in[3] = num_relations (scalar) — R_ hardcoded to 5 per problem setup
    const float* Wq = (const float*)d_in[4];
    const float* bq = (const float*)d_in[5];
    const float* Wk = (const float*)d_in[6];
    const float* bk = (const float*)d_in[7];
    const float* Wv = (const float*)d_in[8];
    const float* bv = (const float*)d_in[9];
    const float* sa = (const float*)d_in[10];
    const float* Wo = (const float*)d_in[11];
    const float* bo = (const float*)d_in[12];
    float* out = (float*)d_out;

    int N = in_sizes[0] / C_;
    int E = in_sizes[2];

    float* ws = (float*)d_ws;
    float* q      = ws;                         // reused as outacc after scores
    float* k      = q + (size_t)N * C_;
    float* v      = k + (size_t)N * C_;
    float* scores = v + (size_t)N * C_;
    int*   m_enc  = (int*)(scores + (size_t)E * H_);
    float* s      = (float*)(m_enc + RH);
    float* alpha  = s + RH;
    int*   cnt    = (int*)(alpha + C_);         // N ints (histogram -> cursor)
    int*   offs   = cnt + N;                    // N+1 ints
    int*   sorted = offs + N + 1;               // E ints
    float* outacc = q;                          // alias: q dead after scores_kernel
    size_t need = (size_t)((char*)(sorted + E) - (char*)d_ws);
    if (ws_size < need) return;   // workspace too small — fail cleanly

    // ---- CSR build (independent of GEMMs) ----
    hipMemsetAsync(cnt, 0, (size_t)N * sizeof(int), stream);
    init_kernel<<<1, 64, 0, stream>>>(sa, m_enc, s, alpha);
    hist_kernel<<<(E + 255) / 256, 256, 0, stream>>>(ei, cnt, E);
    scan_kernel<<<1, 1024, 0, stream>>>(cnt, offs, N);
    fill_kernel<<<(E + 255) / 256, 256, 0, stream>>>(ei, cnt, sorted, E);

    // ---- main pipeline ----
    qkv_kernel<<<(N + 63) / 64, 256, 0, stream>>>(x, Wq, bq, Wk, bk, Wv, bv, q, k, v, N);
    int nb = (E * H_ + 255) / 256;
    scores_kernel<<<nb, 256, 0, stream>>>(q, k, ei, et, scores, m_enc, E);
    expsum_kernel<<<nb, 256, 0, stream>>>(scores, et, m_enc, s, E);
    gather_kernel<<<N, 64, 0, stream>>>(scores, v, ei, et, s, offs, sorted, outacc, E);
    ogemm_kernel<<<(N + 63) / 64, 256, 0, stream>>>(outacc, alpha, Wo, bo, out, N);
}

// Round 3
// 659.762 us; speedup vs baseline: 11.1422x; 2.9228x over previous
//
#include <hip/hip_runtime.h>

constexpr int R_ = 5, H_ = 8, D_ = 16, C_ = 128;
constexpr int RH = R_ * H_;   // 40 softmax slots

// ---- init: s = 0, alpha = softmax(semantic_att, axis=0) ----
__global__ void init_kernel(const float* __restrict__ sa,
                            float* __restrict__ s, float* __restrict__ alpha) {
    int t = threadIdx.x;
    if (t < RH) s[t] = 0.0f;
    if (t < D_) {
        float vals[H_];
        float mx = -1e30f;
        #pragma unroll
        for (int h = 0; h < H_; ++h) { vals[h] = sa[h * D_ + t]; mx = fmaxf(mx, vals[h]); }
        float sum = 0.0f;
        #pragma unroll
        for (int h = 0; h < H_; ++h) { vals[h] = expf(vals[h] - mx); sum += vals[h]; }
        float inv = 1.0f / sum;
        #pragma unroll
        for (int h = 0; h < H_; ++h) alpha[h * D_ + t] = vals[h] * inv;
    }
}

// ---- CSR build: histogram of destination rows ----
__global__ __launch_bounds__(256) void hist_kernel(const int* __restrict__ ei,
                                                   int* __restrict__ cnt, int E) {
    int i = blockIdx.x * 256 + threadIdx.x;
    if (i < E) atomicAdd(&cnt[ei[i]], 1);
}

// ---- CSR build: exclusive scan over N counts (single block) ----
__global__ __launch_bounds__(1024) void scan_kernel(int* __restrict__ cnt,
                                                    int* __restrict__ offs, int N) {
    __shared__ int tot[1024];
    int t = threadIdx.x;
    int chunk = (N + 1023) >> 10;
    int beg = t * chunk;
    int end = min(beg + chunk, N);
    int sum = 0;
    for (int i = beg; i < end; ++i) sum += cnt[i];
    tot[t] = sum;
    __syncthreads();
    for (int d = 1; d < 1024; d <<= 1) {
        int val = (t >= d) ? tot[t - d] : 0;
        __syncthreads();
        tot[t] += val;
        __syncthreads();
    }
    int base = (t == 0) ? 0 : tot[t - 1];
    for (int i = beg; i < end; ++i) {
        int c = cnt[i];
        offs[i] = base;
        cnt[i] = base;    // cursor init for fill pass
        base += c;
    }
    if (t == 1023) offs[N] = base;
}

// ---- CSR build: scatter edge ids into row-sorted order ----
__global__ __launch_bounds__(256) void fill_kernel(const int* __restrict__ ei,
                                                   int* __restrict__ cursor,
                                                   int* __restrict__ sorted, int E) {
    int i = blockIdx.x * 256 + threadIdx.x;
    if (i < E) {
        int pos = atomicAdd(&cursor[ei[i]], 1);
        sorted[pos] = i;
    }
}

// ---- shared GEMM micro-kernel: out[row0.., :] = xs(64x128) @ W^T + b ----
__device__ __forceinline__ void tile_gemm_store(const float* __restrict__ xs,
                                                const float* __restrict__ W,
                                                const float* __restrict__ b,
                                                float* __restrict__ out,
                                                int row0, int N) {
    int tid = threadIdx.x;
    int c0 = (tid & 31) * 4;   // 4 output cols
    int r0 = (tid >> 5) * 8;   // 8 rows
    float acc[8][4];
    float b0 = b[c0], b1 = b[c0 + 1], b2 = b[c0 + 2], b3 = b[c0 + 3];
    #pragma unroll
    for (int r = 0; r < 8; ++r) { acc[r][0] = b0; acc[r][1] = b1; acc[r][2] = b2; acc[r][3] = b3; }
    for (int kk = 0; kk < 128; kk += 4) {
        float4 w0 = *(const float4*)(W + (c0 + 0) * C_ + kk);
        float4 w1 = *(const float4*)(W + (c0 + 1) * C_ + kk);
        float4 w2 = *(const float4*)(W + (c0 + 2) * C_ + kk);
        float4 w3 = *(const float4*)(W + (c0 + 3) * C_ + kk);
        #pragma unroll
        for (int r = 0; r < 8; ++r) {
            float4 xv = *(const float4*)(xs + (r0 + r) * C_ + kk);
            acc[r][0] += xv.x * w0.x + xv.y * w0.y + xv.z * w0.z + xv.w * w0.w;
            acc[r][1] += xv.x * w1.x + xv.y * w1.y + xv.z * w1.z + xv.w * w1.w;
            acc[r][2] += xv.x * w2.x + xv.y * w2.y + xv.z * w2.z + xv.w * w2.w;
            acc[r][3] += xv.x * w3.x + xv.y * w3.y + xv.z * w3.z + xv.w * w3.w;
        }
    }
    #pragma unroll
    for (int r = 0; r < 8; ++r) {
        int grow = row0 + r0 + r;
        if (grow < N) {
            float4 o = make_float4(acc[r][0], acc[r][1], acc[r][2], acc[r][3]);
            *(float4*)(out + (size_t)grow * C_ + c0) = o;
        }
    }
}

// ---- fused q/k/v GEMM: x tile staged once, reused for 3 weight matrices ----
__global__ __launch_bounds__(256) void qkv_kernel(const float* __restrict__ x,
                                                  const float* __restrict__ Wq, const float* __restrict__ bq,
                                                  const float* __restrict__ Wk, const float* __restrict__ bk,
                                                  const float* __restrict__ Wv, const float* __restrict__ bv,
                                                  float* __restrict__ q, float* __restrict__ k,
                                                  float* __restrict__ v, int N) {
    __shared__ float xs[64 * 128];
    int row0 = blockIdx.x * 64;
    int tid = threadIdx.x;
    #pragma unroll
    for (int j = 0; j < 8; ++j) {
        int f = tid + j * 256;       // float4 index within tile (2048 total)
        int r = f >> 5, c4 = f & 31;
        int grow = row0 + r;
        float4 val = make_float4(0.f, 0.f, 0.f, 0.f);
        if (grow < N) val = *(const float4*)(x + (size_t)grow * C_ + c4 * 4);
        *(float4*)(xs + r * C_ + c4 * 4) = val;
    }
    __syncthreads();
    tile_gemm_store(xs, Wq, bq, q, row0, N);
    tile_gemm_store(xs, Wk, bk, k, row0, N);
    tile_gemm_store(xs, Wv, bv, v, row0, N);
}

// ---- fused: scores = exp(q[row]·k[col]/4) + segment sum over (relation, head) ----
// No max-subtraction: scores ~ N(0,1) (max over 160k ~ 5), exp cannot overflow,
// and attn = e/s is exactly invariant to the per-segment shift.
__global__ __launch_bounds__(256) void scores_exp_kernel(const float* __restrict__ q,
                                                         const float* __restrict__ k,
                                                         const int* __restrict__ ei,
                                                         const int* __restrict__ et,
                                                         float* __restrict__ scores,
                                                         float* __restrict__ s, int E) {
    __shared__ float lsum[RH];
    int tid = threadIdx.x;
    if (tid < RH) lsum[tid] = 0.f;
    __syncthreads();
    int total = E * H_;
    int stride = gridDim.x * 256;
    for (int i = blockIdx.x * 256 + tid; i < total; i += stride) {
        int e = i >> 3, h = i & 7;
        int r = ei[e], c = ei[E + e], t = et[e];
        const float4* qp = (const float4*)(q + (size_t)r * C_ + h * D_);
        const float4* kp = (const float4*)(k + (size_t)c * C_ + h * D_);
        float acc = 0.f;
        #pragma unroll
        for (int j = 0; j < 4; ++j) {
            float4 a = qp[j], b = kp[j];
            acc += a.x * b.x + a.y * b.y + a.z * b.z + a.w * b.w;
        }
        float val = __expf(acc * 0.25f);    // 1/sqrt(16)
        scores[i] = val;
        atomicAdd(&lsum[t * H_ + h], val);
    }
    __syncthreads();
    if (tid < RH) atomicAdd(&s[tid], lsum[tid]);
}

// ---- gather: out[row] = sum over incoming edges of attn * v[col], no atomics ----
__global__ __launch_bounds__(64) void gather_kernel(const float* __restrict__ scores,
                                                    const float* __restrict__ v,
                                                    const int* __restrict__ ei,
                                                    const int* __restrict__ et,
                                                    const float* __restrict__ s,
                                                    const int* __restrict__ offs,
                                                    const int* __restrict__ sorted,
                                                    float* __restrict__ outacc, int E) {
    __shared__ float sinv[RH];
    int tid = threadIdx.x;
    if (tid < RH) { float sv = s[tid]; sinv[tid] = sv > 0.f ? 1.f / sv : 0.f; }
    __syncthreads();
    int row = blockIdx.x;
    int beg = offs[row], end = offs[row + 1];
    int c0 = tid * 2;            // two output channels per lane
    int h = c0 >> 4;             // head for both channels
    float ax = 0.f, ay = 0.f;
    int j = beg;
    for (; j + 1 < end; j += 2) {
        int e0 = sorted[j], e1 = sorted[j + 1];
        int col0 = ei[E + e0], col1 = ei[E + e1];
        int t0 = et[e0], t1 = et[e1];
        float a0 = scores[e0 * H_ + h] * sinv[t0 * H_ + h];
        float a1 = scores[e1 * H_ + h] * sinv[t1 * H_ + h];
        float2 m0 = *(const float2*)(v + (size_t)col0 * C_ + c0);
        float2 m1 = *(const float2*)(v + (size_t)col1 * C_ + c0);
        ax += m0.x * a0 + m1.x * a1;
        ay += m0.y * a0 + m1.y * a1;
    }
    if (j < end) {
        int e0 = sorted[j];
        int col0 = ei[E + e0];
        int t0 = et[e0];
        float a0 = scores[e0 * H_ + h] * sinv[t0 * H_ + h];
        float2 m0 = *(const float2*)(v + (size_t)col0 * C_ + c0);
        ax += m0.x * a0;
        ay += m0.y * a0;
    }
    *(float2*)(outacc + (size_t)row * C_ + c0) = make_float2(ax, ay);
}

// ---- final GEMM: out = (outacc * alpha) @ Wo^T + bo ----
__global__ __launch_bounds__(256) void ogemm_kernel(const float* __restrict__ outacc,
                                                    const float* __restrict__ alpha,
                                                    const float* __restrict__ Wo,
                                                    const float* __restrict__ bo,
                                                    float* __restrict__ out, int N) {
    __shared__ float xs[64 * 128];
    int row0 = blockIdx.x * 64;
    int tid = threadIdx.x;
    #pragma unroll
    for (int j = 0; j < 8; ++j) {
        int f = tid + j * 256;
        int r = f >> 5, c4 = f & 31;
        int grow = row0 + r;
        float4 val = make_float4(0.f, 0.f, 0.f, 0.f);
        if (grow < N) {
            val = *(const float4*)(outacc + (size_t)grow * C_ + c4 * 4);
            float4 al = *(const float4*)(alpha + c4 * 4);
            val.x *= al.x; val.y *= al.y; val.z *= al.z; val.w *= al.w;
        }
        *(float4*)(xs + r * C_ + c4 * 4) = val;
    }
    __syncthreads();
    tile_gemm_store(xs, Wo, bo, out, row0, N);
}

extern "C" void kernel_launch(void* const* d_in, const int* in_sizes, int n_in,
                              void* d_out, int out_size, void* d_ws, size_t ws_size,
                              hipStream_t stream) {
    const float* x  = (const float*)d_in[0];
    const int*   ei = (const int*)d_in[1];
    const int*   et = (const int*)d_in[2];
    // d_in[3] = num_relations (scalar) — R_ hardcoded to 5 per problem setup
    const float* Wq = (const float*)d_in[4];
    const float* bq = (const float*)d_in[5];
    const float* Wk = (const float*)d_in[6];
    const float* bk = (const float*)d_in[7];
    const float* Wv = (const float*)d_in[8];
    const float* bv = (const float*)d_in[9];
    const float* sa = (const float*)d_in[10];
    const float* Wo = (const float*)d_in[11];
    const float* bo = (const float*)d_in[12];
    float* out = (float*)d_out;

    int N = in_sizes[0] / C_;
    int E = in_sizes[2];

    float* ws = (float*)d_ws;
    float* q      = ws;                         // reused as outacc after scores
    float* k      = q + (size_t)N * C_;
    float* v      = k + (size_t)N * C_;
    float* scores = v + (size_t)N * C_;
    float* s      = scores + (size_t)E * H_;
    float* alpha  = s + RH;
    int*   cnt    = (int*)(alpha + C_);         // N ints (histogram -> cursor)
    int*   offs   = cnt + N;                    // N+1 ints
    int*   sorted = offs + N + 1;               // E ints
    float* outacc = q;                          // alias: q dead after scores_exp
    size_t need = (size_t)((char*)(sorted + E) - (char*)d_ws);
    if (ws_size < need) return;   // workspace too small — fail cleanly

    // ---- CSR build (independent of GEMMs) ----
    hipMemsetAsync(cnt, 0, (size_t)N * sizeof(int), stream);
    init_kernel<<<1, 64, 0, stream>>>(sa, s, alpha);
    hist_kernel<<<(E + 255) / 256, 256, 0, stream>>>(ei, cnt, E);
    scan_kernel<<<1, 1024, 0, stream>>>(cnt, offs, N);
    fill_kernel<<<(E + 255) / 256, 256, 0, stream>>>(ei, cnt, sorted, E);

    // ---- main pipeline ----
    qkv_kernel<<<(N + 63) / 64, 256, 0, stream>>>(x, Wq, bq, Wk, bk, Wv, bv, q, k, v, N);
    scores_exp_kernel<<<2048, 256, 0, stream>>>(q, k, ei, et, scores, s, E);
    gather_kernel<<<N, 64, 0, stream>>>(scores, v, ei, et, s, offs, sorted, outacc, E);
    ogemm_kernel<<<(N + 63) / 64, 256, 0, stream>>>(outacc, alpha, Wo, bo, out, N);
}

// Round 4
// 498.053 us; speedup vs baseline: 14.7599x; 1.3247x over previous
//
#include <hip/hip_runtime.h>

constexpr int R_ = 5, H_ = 8, D_ = 16, C_ = 128;
constexpr int RH = R_ * H_;   // 40 softmax slots

typedef short bf16x8 __attribute__((ext_vector_type(8)));
typedef float f32x4 __attribute__((ext_vector_type(4)));

__device__ __forceinline__ unsigned short f2bf(float f) {
    unsigned int u = __float_as_uint(f);
    u += 0x7FFFu + ((u >> 16) & 1u);   // round-to-nearest-even
    return (unsigned short)(u >> 16);
}

// ---- init: s = 0, alpha = softmax(semantic_att, axis=0) ----
__global__ void init_kernel(const float* __restrict__ sa,
                            float* __restrict__ s, float* __restrict__ alpha) {
    int t = threadIdx.x;
    if (t < RH) s[t] = 0.0f;
    if (t < D_) {
        float vals[H_];
        float mx = -1e30f;
        #pragma unroll
        for (int h = 0; h < H_; ++h) { vals[h] = sa[h * D_ + t]; mx = fmaxf(mx, vals[h]); }
        float sum = 0.0f;
        #pragma unroll
        for (int h = 0; h < H_; ++h) { vals[h] = expf(vals[h] - mx); sum += vals[h]; }
        float inv = 1.0f / sum;
        #pragma unroll
        for (int h = 0; h < H_; ++h) alpha[h * D_ + t] = vals[h] * inv;
    }
}

// ---- convert Wq/Wk/Wv/Wo to bf16 once ----
__global__ __launch_bounds__(256) void wprep_kernel(const float* __restrict__ Wq,
                                                    const float* __restrict__ Wk,
                                                    const float* __restrict__ Wv,
                                                    const float* __restrict__ Wo,
                                                    unsigned short* __restrict__ w3,
                                                    unsigned short* __restrict__ wo) {
    int i = blockIdx.x * 256 + threadIdx.x;
    if (i < 16384) {
        w3[i]           = f2bf(Wq[i]);
        w3[16384 + i]   = f2bf(Wk[i]);
        w3[32768 + i]   = f2bf(Wv[i]);
        wo[i]           = f2bf(Wo[i]);
    }
}

// ---- CSR build: histogram of destination rows ----
__global__ __launch_bounds__(256) void hist_kernel(const int* __restrict__ ei,
                                                   int* __restrict__ cnt, int E) {
    int i = blockIdx.x * 256 + threadIdx.x;
    if (i < E) atomicAdd(&cnt[ei[i]], 1);
}

// ---- CSR build: exclusive scan over N counts (single block) ----
__global__ __launch_bounds__(1024) void scan_kernel(int* __restrict__ cnt,
                                                    int* __restrict__ offs, int N) {
    __shared__ int tot[1024];
    int t = threadIdx.x;
    int chunk = (N + 1023) >> 10;
    int beg = t * chunk;
    int end = min(beg + chunk, N);
    int sum = 0;
    for (int i = beg; i < end; ++i) sum += cnt[i];
    tot[t] = sum;
    __syncthreads();
    for (int d = 1; d < 1024; d <<= 1) {
        int val = (t >= d) ? tot[t - d] : 0;
        __syncthreads();
        tot[t] += val;
        __syncthreads();
    }
    int base = (t == 0) ? 0 : tot[t - 1];
    for (int i = beg; i < end; ++i) {
        int c = cnt[i];
        offs[i] = base;
        cnt[i] = base;    // cursor init for fill pass
        base += c;
    }
    if (t == 1023) offs[N] = base;
}

// ---- CSR build: scatter edge ids into row-sorted order ----
__global__ __launch_bounds__(256) void fill_kernel(const int* __restrict__ ei,
                                                   int* __restrict__ cursor,
                                                   int* __restrict__ sorted, int E) {
    int i = blockIdx.x * 256 + threadIdx.x;
    if (i < E) {
        int pos = atomicAdd(&cursor[ei[i]], 1);
        sorted[pos] = i;
    }
}

// ============ MFMA GEMM: 64-row tile, 4 waves, wave = 16 rows x 128 cols ============
// LDS tile As[64][128] bf16, XOR-swizzled: byte ^= (row&7)<<4 (T2, conflict-free
// 16-lane row-strided ds_read_b128). B fragments live in registers from L2.

// stage 64x128 fp32 rows -> bf16 swizzled LDS (optionally scaled per-channel)
__device__ __forceinline__ void stage_tile(unsigned short* As, const float* __restrict__ src,
                                           const float* __restrict__ scale, int row0, int N) {
    int tid = threadIdx.x;
    #pragma unroll
    for (int it = 0; it < 4; ++it) {
        int g = tid + it * 256;       // 1024 groups of 8 bf16 (16B)
        int row = g >> 4, kg = g & 15;
        int grow = row0 + row;
        float4 f0 = make_float4(0.f, 0.f, 0.f, 0.f), f1 = f0;
        if (grow < N) {
            const float* p = src + (size_t)grow * C_ + kg * 8;
            f0 = *(const float4*)p;
            f1 = *(const float4*)(p + 4);
            if (scale) {
                float4 a0 = *(const float4*)(scale + kg * 8);
                float4 a1 = *(const float4*)(scale + kg * 8 + 4);
                f0.x *= a0.x; f0.y *= a0.y; f0.z *= a0.z; f0.w *= a0.w;
                f1.x *= a1.x; f1.y *= a1.y; f1.z *= a1.z; f1.w *= a1.w;
            }
        }
        uint4 pk;
        pk.x = f2bf(f0.x) | ((unsigned int)f2bf(f0.y) << 16);
        pk.y = f2bf(f0.z) | ((unsigned int)f2bf(f0.w) << 16);
        pk.z = f2bf(f1.x) | ((unsigned int)f2bf(f1.y) << 16);
        pk.w = f2bf(f1.z) | ((unsigned int)f2bf(f1.w) << 16);
        *(uint4*)((char*)As + (row * 256 + ((kg * 16) ^ ((row & 7) << 4)))) = pk;
    }
}

// wave GEMM body: acc[n] over 8 col-tiles; A from LDS, B frags from global bf16 W
__device__ __forceinline__ void wave_gemm(const unsigned short* As,
                                          const unsigned short* __restrict__ W,
                                          const float* __restrict__ bias,
                                          float* __restrict__ out, int row0, int N) {
    int tid = threadIdx.x;
    int l = tid & 63, wave = tid >> 6;
    int lr = l & 15, lk = (l >> 4) * 8;
    bf16x8 bfr[8][4];
    #pragma unroll
    for (int n = 0; n < 8; ++n)
        #pragma unroll
        for (int kk = 0; kk < 4; ++kk)
            bfr[n][kk] = *(const bf16x8*)(W + (n * 16 + lr) * C_ + kk * 32 + lk);
    f32x4 acc[8];
    #pragma unroll
    for (int n = 0; n < 8; ++n) acc[n] = (f32x4){0.f, 0.f, 0.f, 0.f};
    int rowA = wave * 16 + lr;
    const char* abase = (const char*)As + rowA * 256;
    int sw = (rowA & 7) << 4;
    #pragma unroll
    for (int kk = 0; kk < 4; ++kk) {
        bf16x8 a = *(const bf16x8*)(abase + (((kk * 32 + lk) * 2) ^ sw));
        #pragma unroll
        for (int n = 0; n < 8; ++n)
            acc[n] = __builtin_amdgcn_mfma_f32_16x16x32_bf16(a, bfr[n][kk], acc[n], 0, 0, 0);
    }
    // C/D: col = lane&15, row = (lane>>4)*4 + reg   [m89]
    int rbase = row0 + wave * 16 + (l >> 4) * 4;
    #pragma unroll
    for (int n = 0; n < 8; ++n) {
        int col = n * 16 + lr;
        float bc = bias[col];
        #pragma unroll
        for (int r = 0; r < 4; ++r) {
            int grow = rbase + r;
            if (grow < N) out[(size_t)grow * C_ + col] = acc[n][r] + bc;
        }
    }
}

// qkv: grid = nrt*3, rt-major (3 weight variants of a tile adjacent for x reuse)
__global__ __launch_bounds__(256) void qkv_mfma(const float* __restrict__ x,
                                                const unsigned short* __restrict__ w3,
                                                const float* __restrict__ bq,
                                                const float* __restrict__ bk,
                                                const float* __restrict__ bv,
                                                float* __restrict__ q, float* __restrict__ k,
                                                float* __restrict__ v, int N) {
    __shared__ unsigned short As[64 * 128];
    int bid = blockIdx.x;
    int rt = bid / 3, wsel = bid - rt * 3;
    int row0 = rt * 64;
    const unsigned short* W = w3 + wsel * 16384;
    const float* bias = wsel == 0 ? bq : (wsel == 1 ? bk : bv);
    float* out = wsel == 0 ? q : (wsel == 1 ? k : v);
    stage_tile(As, x, nullptr, row0, N);
    __syncthreads();
    wave_gemm(As, W, bias, out, row0, N);
}

// final GEMM: out = (outacc * alpha) @ Wo^T + bo
__global__ __launch_bounds__(256) void ogemm_mfma(const float* __restrict__ outacc,
                                                  const float* __restrict__ alpha,
                                                  const unsigned short* __restrict__ wo,
                                                  const float* __restrict__ bo,
                                                  float* __restrict__ out, int N) {
    __shared__ unsigned short As[64 * 128];
    int row0 = blockIdx.x * 64;
    stage_tile(As, outacc, alpha, row0, N);
    __syncthreads();
    wave_gemm(As, wo, bo, out, row0, N);
}

// ---- fused: scores = exp(q[row]·k[col]/4) + segment sum over (relation, head) ----
__global__ __launch_bounds__(256) void scores_exp_kernel(const float* __restrict__ q,
                                                         const float* __restrict__ k,
                                                         const int* __restrict__ ei,
                                                         const int* __restrict__ et,
                                                         float* __restrict__ scores,
                                                         float* __restrict__ s, int E) {
    __shared__ float lsum[RH];
    int tid = threadIdx.x;
    if (tid < RH) lsum[tid] = 0.f;
    __syncthreads();
    int total = E * H_;
    int stride = gridDim.x * 256;
    for (int i = blockIdx.x * 256 + tid; i < total; i += stride) {
        int e = i >> 3, h = i & 7;
        int r = ei[e], c = ei[E + e], t = et[e];
        const float4* qp = (const float4*)(q + (size_t)r * C_ + h * D_);
        const float4* kp = (const float4*)(k + (size_t)c * C_ + h * D_);
        float acc = 0.f;
        #pragma unroll
        for (int j = 0; j < 4; ++j) {
            float4 a = qp[j], b = kp[j];
            acc += a.x * b.x + a.y * b.y + a.z * b.z + a.w * b.w;
        }
        float val = __expf(acc * 0.25f);    // 1/sqrt(16)
        scores[i] = val;
        atomicAdd(&lsum[t * H_ + h], val);
    }
    __syncthreads();
    if (tid < RH) atomicAdd(&s[tid], lsum[tid]);
}

// ---- gather: out[row] = sum over incoming edges of attn * v[col], no atomics ----
__global__ __launch_bounds__(64) void gather_kernel(const float* __restrict__ scores,
                                                    const float* __restrict__ v,
                                                    const int* __restrict__ ei,
                                                    const int* __restrict__ et,
                                                    const float* __restrict__ s,
                                                    const int* __restrict__ offs,
                                                    const int* __restrict__ sorted,
                                                    float* __restrict__ outacc, int E) {
    __shared__ float sinv[RH];
    int tid = threadIdx.x;
    if (tid < RH) { float sv = s[tid]; sinv[tid] = sv > 0.f ? 1.f / sv : 0.f; }
    __syncthreads();
    int row = blockIdx.x;
    int beg = offs[row], end = offs[row + 1];
    int c0 = tid * 2;            // two output channels per lane
    int h = c0 >> 4;             // head for both channels
    float ax = 0.f, ay = 0.f;
    int j = beg;
    for (; j + 1 < end; j += 2) {
        int e0 = sorted[j], e1 = sorted[j + 1];
        int col0 = ei[E + e0], col1 = ei[E + e1];
        int t0 = et[e0], t1 = et[e1];
        float a0 = scores[e0 * H_ + h] * sinv[t0 * H_ + h];
        float a1 = scores[e1 * H_ + h] * sinv[t1 * H_ + h];
        float2 m0 = *(const float2*)(v + (size_t)col0 * C_ + c0);
        float2 m1 = *(const float2*)(v + (size_t)col1 * C_ + c0);
        ax += m0.x * a0 + m1.x * a1;
        ay += m0.y * a0 + m1.y * a1;
    }
    if (j < end) {
        int e0 = sorted[j];
        int col0 = ei[E + e0];
        int t0 = et[e0];
        float a0 = scores[e0 * H_ + h] * sinv[t0 * H_ + h];
        float2 m0 = *(const float2*)(v + (size_t)col0 * C_ + c0);
        ax += m0.x * a0;
        ay += m0.y * a0;
    }
    *(float2*)(outacc + (size_t)row * C_ + c0) = make_float2(ax, ay);
}

extern "C" void kernel_launch(void* const* d_in, const int* in_sizes, int n_in,
                              void* d_out, int out_size, void* d_ws, size_t ws_size,
                              hipStream_t stream) {
    const float* x  = (const float*)d_in[0];
    const int*   ei = (const int*)d_in[1];
    const int*   et = (const int*)d_in[2];
    // d_in[3] = num_relations (scalar) — R_ hardcoded to 5 per problem setup
    const float* Wq = (const float*)d_in[4];
    const float* bq = (const float*)d_in[5];
    const float* Wk = (const float*)d_in[6];
    const float* bk = (const float*)d_in[7];
    const float* Wv = (const float*)d_in[8];
    const float* bv = (const float*)d_in[9];
    const float* sa = (const float*)d_in[10];
    const float* Wo = (const float*)d_in[11];
    const float* bo = (const float*)d_in[12];
    float* out = (float*)d_out;

    int N = in_sizes[0] / C_;
    int E = in_sizes[2];

    float* ws = (float*)d_ws;
    float* q      = ws;                         // reused as outacc after scores
    float* k      = q + (size_t)N * C_;
    float* v      = k + (size_t)N * C_;
    float* scores = v + (size_t)N * C_;
    float* s      = scores + (size_t)E * H_;
    float* alpha  = s + RH;
    int*   cnt    = (int*)(alpha + C_);         // N ints (histogram -> cursor)
    int*   offs   = cnt + N;                    // N+1 ints
    int*   sorted = offs + N + 1;               // E ints
    unsigned short* w3 = (unsigned short*)(sorted + E);  // 3*16384 bf16
    unsigned short* wo = w3 + 3 * 16384;                 // 16384 bf16
    float* outacc = q;                          // alias: q dead after scores_exp
    size_t need = (size_t)((char*)(wo + 16384) - (char*)d_ws);
    if (ws_size < need) return;   // workspace too small — fail cleanly

    // ---- prep: weights to bf16, CSR build (independent of GEMMs) ----
    hipMemsetAsync(cnt, 0, (size_t)N * sizeof(int), stream);
    init_kernel<<<1, 64, 0, stream>>>(sa, s, alpha);
    wprep_kernel<<<64, 256, 0, stream>>>(Wq, Wk, Wv, Wo, w3, wo);
    hist_kernel<<<(E + 255) / 256, 256, 0, stream>>>(ei, cnt, E);
    scan_kernel<<<1, 1024, 0, stream>>>(cnt, offs, N);
    fill_kernel<<<(E + 255) / 256, 256, 0, stream>>>(ei, cnt, sorted, E);

    // ---- main pipeline ----
    int nrt = (N + 63) / 64;
    qkv_mfma<<<nrt * 3, 256, 0, stream>>>(x, w3, bq, bk, bv, q, k, v, N);
    scores_exp_kernel<<<2048, 256, 0, stream>>>(q, k, ei, et, scores, s, E);
    gather_kernel<<<N, 64, 0, stream>>>(scores, v, ei, et, s, offs, sorted, outacc, E);
    ogemm_mfma<<<nrt, 256, 0, stream>>>(outacc, alpha, wo, bo, out, N);
}

// Round 6
// 404.987 us; speedup vs baseline: 18.1517x; 1.2298x over previous
//
#include <hip/hip_runtime.h>

constexpr int R_ = 5, H_ = 8, D_ = 16, C_ = 128;
constexpr int RH = R_ * H_;   // 40 softmax slots

typedef short bf16x8 __attribute__((ext_vector_type(8)));
typedef float f32x4 __attribute__((ext_vector_type(4)));

__device__ __forceinline__ unsigned short f2bf(float f) {
    unsigned int u = __float_as_uint(f);
    u += 0x7FFFu + ((u >> 16) & 1u);   // round-to-nearest-even
    return (unsigned short)(u >> 16);
}
__device__ __forceinline__ float bf2f(unsigned short b) {
    return __uint_as_float((unsigned int)b << 16);
}

// ---- init: s = 0, alpha = softmax(semantic_att, axis=0) ----
__global__ void init_kernel(const float* __restrict__ sa,
                            float* __restrict__ s, float* __restrict__ alpha) {
    int t = threadIdx.x;
    if (t < RH) s[t] = 0.0f;
    if (t < D_) {
        float vals[H_];
        float mx = -1e30f;
        #pragma unroll
        for (int h = 0; h < H_; ++h) { vals[h] = sa[h * D_ + t]; mx = fmaxf(mx, vals[h]); }
        float sum = 0.0f;
        #pragma unroll
        for (int h = 0; h < H_; ++h) { vals[h] = expf(vals[h] - mx); sum += vals[h]; }
        float inv = 1.0f / sum;
        #pragma unroll
        for (int h = 0; h < H_; ++h) alpha[h * D_ + t] = vals[h] * inv;
    }
}

// ---- convert Wq/Wk/Wv/Wo to bf16 once ----
__global__ __launch_bounds__(256) void wprep_kernel(const float* __restrict__ Wq,
                                                    const float* __restrict__ Wk,
                                                    const float* __restrict__ Wv,
                                                    const float* __restrict__ Wo,
                                                    unsigned short* __restrict__ w3,
                                                    unsigned short* __restrict__ wo) {
    int i = blockIdx.x * 256 + threadIdx.x;
    if (i < 16384) {
        w3[i]           = f2bf(Wq[i]);
        w3[16384 + i]   = f2bf(Wk[i]);
        w3[32768 + i]   = f2bf(Wv[i]);
        wo[i]           = f2bf(Wo[i]);
    }
}

// ---- CSR build: histogram of destination rows ----
__global__ __launch_bounds__(256) void hist_kernel(const int* __restrict__ ei,
                                                   int* __restrict__ cnt, int E) {
    int i = blockIdx.x * 256 + threadIdx.x;
    if (i < E) atomicAdd(&cnt[ei[i]], 1);
}

// ---- CSR build: exclusive scan over N counts (single block) ----
__global__ __launch_bounds__(1024) void scan_kernel(int* __restrict__ cnt,
                                                    int* __restrict__ offs, int N) {
    __shared__ int tot[1024];
    int t = threadIdx.x;
    int chunk = (N + 1023) >> 10;
    int beg = t * chunk;
    int end = min(beg + chunk, N);
    int sum = 0;
    for (int i = beg; i < end; ++i) sum += cnt[i];
    tot[t] = sum;
    __syncthreads();
    for (int d = 1; d < 1024; d <<= 1) {
        int val = (t >= d) ? tot[t - d] : 0;
        __syncthreads();
        tot[t] += val;
        __syncthreads();
    }
    int base = (t == 0) ? 0 : tot[t - 1];
    for (int i = beg; i < end; ++i) {
        int c = cnt[i];
        offs[i] = base;
        cnt[i] = base;    // cursor init for fill pass
        base += c;
    }
    if (t == 1023) offs[N] = base;
}

// ---- CSR build: emit row-sorted edge metadata (row, col|type packed) ----
__global__ __launch_bounds__(256) void fill_kernel(const int* __restrict__ ei,
                                                   const int* __restrict__ et,
                                                   int* __restrict__ cursor,
                                                   int* __restrict__ row_s,
                                                   int* __restrict__ cstp, int E) {
    int i = blockIdx.x * 256 + threadIdx.x;
    if (i < E) {
        int row = ei[i];
        int pos = atomicAdd(&cursor[row], 1);
        row_s[pos] = row;
        cstp[pos] = ei[E + i] | (et[i] << 20);
    }
}

// ============ MFMA GEMM: 64-row tile, 4 waves, wave = 16 rows x 128 cols ============
// LDS tile As[64][128] bf16, XOR-swizzled: byte ^= (row&7)<<4 (T2, conflict-free
// 16-lane row-strided ds_read_b128). B fragments live in registers from L2.

// stage 64x128 fp32 rows -> bf16 swizzled LDS (optionally scaled per-channel)
__device__ __forceinline__ void stage_tile(unsigned short* As, const float* __restrict__ src,
                                           const float* __restrict__ scale, int row0, int N) {
    int tid = threadIdx.x;
    #pragma unroll
    for (int it = 0; it < 4; ++it) {
        int g = tid + it * 256;       // 1024 groups of 8 bf16 (16B)
        int row = g >> 4, kg = g & 15;
        int grow = row0 + row;
        float4 f0 = make_float4(0.f, 0.f, 0.f, 0.f), f1 = f0;
        if (grow < N) {
            const float* p = src + (size_t)grow * C_ + kg * 8;
            f0 = *(const float4*)p;
            f1 = *(const float4*)(p + 4);
            if (scale) {
                float4 a0 = *(const float4*)(scale + kg * 8);
                float4 a1 = *(const float4*)(scale + kg * 8 + 4);
                f0.x *= a0.x; f0.y *= a0.y; f0.z *= a0.z; f0.w *= a0.w;
                f1.x *= a1.x; f1.y *= a1.y; f1.z *= a1.z; f1.w *= a1.w;
            }
        }
        uint4 pk;
        pk.x = f2bf(f0.x) | ((unsigned int)f2bf(f0.y) << 16);
        pk.y = f2bf(f0.z) | ((unsigned int)f2bf(f0.w) << 16);
        pk.z = f2bf(f1.x) | ((unsigned int)f2bf(f1.y) << 16);
        pk.w = f2bf(f1.z) | ((unsigned int)f2bf(f1.w) << 16);
        *(uint4*)((char*)As + (row * 256 + ((kg * 16) ^ ((row & 7) << 4)))) = pk;
    }
}

// wave GEMM body: acc[n] over 8 col-tiles; A from LDS, B frags from global bf16 W
template <bool BF_OUT>
__device__ __forceinline__ void wave_gemm(const unsigned short* As,
                                          const unsigned short* __restrict__ W,
                                          const float* __restrict__ bias,
                                          float* __restrict__ outf,
                                          unsigned short* __restrict__ outb,
                                          int row0, int N) {
    int tid = threadIdx.x;
    int l = tid & 63, wave = tid >> 6;
    int lr = l & 15, lk = (l >> 4) * 8;
    bf16x8 bfr[8][4];
    #pragma unroll
    for (int n = 0; n < 8; ++n)
        #pragma unroll
        for (int kk = 0; kk < 4; ++kk)
            bfr[n][kk] = *(const bf16x8*)(W + (n * 16 + lr) * C_ + kk * 32 + lk);
    f32x4 acc[8];
    #pragma unroll
    for (int n = 0; n < 8; ++n) acc[n] = (f32x4){0.f, 0.f, 0.f, 0.f};
    int rowA = wave * 16 + lr;
    const char* abase = (const char*)As + rowA * 256;
    int sw = (rowA & 7) << 4;
    #pragma unroll
    for (int kk = 0; kk < 4; ++kk) {
        bf16x8 a = *(const bf16x8*)(abase + (((kk * 32 + lk) * 2) ^ sw));
        #pragma unroll
        for (int n = 0; n < 8; ++n)
            acc[n] = __builtin_amdgcn_mfma_f32_16x16x32_bf16(a, bfr[n][kk], acc[n], 0, 0, 0);
    }
    // C/D: col = lane&15, row = (lane>>4)*4 + reg   [m89]
    int rbase = row0 + wave * 16 + (l >> 4) * 4;
    #pragma unroll
    for (int n = 0; n < 8; ++n) {
        int col = n * 16 + lr;
        float bc = bias[col];
        #pragma unroll
        for (int r = 0; r < 4; ++r) {
            int grow = rbase + r;
            if (grow < N) {
                float val = acc[n][r] + bc;
                if (BF_OUT) outb[(size_t)grow * C_ + col] = f2bf(val);
                else        outf[(size_t)grow * C_ + col] = val;
            }
        }
    }
}

// qkv: grid = nrt*3, rt-major (3 weight variants of a tile adjacent for x reuse)
__global__ __launch_bounds__(256) void qkv_mfma(const float* __restrict__ x,
                                                const unsigned short* __restrict__ w3,
                                                const float* __restrict__ bq,
                                                const float* __restrict__ bk,
                                                const float* __restrict__ bv,
                                                float* __restrict__ q, float* __restrict__ k,
                                                unsigned short* __restrict__ v_bf, int N) {
    __shared__ unsigned short As[64 * 128];
    int bid = blockIdx.x;
    int rt = bid / 3, wsel = bid - rt * 3;
    int row0 = rt * 64;
    const unsigned short* W = w3 + wsel * 16384;
    stage_tile(As, x, nullptr, row0, N);
    __syncthreads();
    if (wsel == 0)      wave_gemm<false>(As, W, bq, q, nullptr, row0, N);
    else if (wsel == 1) wave_gemm<false>(As, W, bk, k, nullptr, row0, N);
    else                wave_gemm<true>(As, W, bv, nullptr, v_bf, row0, N);
}

// final GEMM: out = (outacc * alpha) @ Wo^T + bo
__global__ __launch_bounds__(256) void ogemm_mfma(const float* __restrict__ outacc,
                                                  const float* __restrict__ alpha,
                                                  const unsigned short* __restrict__ wo,
                                                  const float* __restrict__ bo,
                                                  float* __restrict__ out, int N) {
    __shared__ unsigned short As[64 * 128];
    int row0 = blockIdx.x * 64;
    stage_tile(As, outacc, alpha, row0, N);
    __syncthreads();
    wave_gemm<false>(As, wo, bo, out, nullptr, row0, N);
}

// ---- fused: scores_s[j] = exp(q[row_s[j]]·k[col]/4), row-sorted order,
//      + segment sum over (relation, head). q-side is L1-local (sorted runs). ----
__global__ __launch_bounds__(256) void scores_exp_kernel(const float* __restrict__ q,
                                                         const float* __restrict__ k,
                                                         const int* __restrict__ row_s,
                                                         const int* __restrict__ cstp,
                                                         float* __restrict__ scores_s,
                                                         float* __restrict__ s, int E) {
    __shared__ float lsum[RH];
    int tid = threadIdx.x;
    if (tid < RH) lsum[tid] = 0.f;
    __syncthreads();
    int total = E * H_;
    int stride = gridDim.x * 256;
    for (int i = blockIdx.x * 256 + tid; i < total; i += stride) {
        int j = i >> 3, h = i & 7;
        int row = row_s[j];
        int m = cstp[j];
        int col = m & 0xFFFFF, t = m >> 20;
        const float4* qp = (const float4*)(q + (size_t)row * C_ + h * D_);
        const float4* kp = (const float4*)(k + (size_t)col * C_ + h * D_);
        float acc = 0.f;
        #pragma unroll
        for (int jj = 0; jj < 4; ++jj) {
            float4 a = qp[jj], b = kp[jj];
            acc += a.x * b.x + a.y * b.y + a.z * b.z + a.w * b.w;
        }
        float val = __expf(acc * 0.25f);    // 1/sqrt(16)
        scores_s[i] = val;
        atomicAdd(&lsum[t * H_ + h], val);
    }
    __syncthreads();
    if (tid < RH) atomicAdd(&s[tid], lsum[tid]);
}

// ---- gather: out[row] = sum over row's edges of attn * v[col]; scores contiguous ----
__global__ __launch_bounds__(64) void gather_kernel(const float* __restrict__ scores_s,
                                                    const unsigned short* __restrict__ v_bf,
                                                    const int* __restrict__ cstp,
                                                    const float* __restrict__ s,
                                                    const int* __restrict__ offs,
                                                    float* __restrict__ outacc) {
    __shared__ float sinv[RH];
    int tid = threadIdx.x;
    if (tid < RH) { float sv = s[tid]; sinv[tid] = sv > 0.f ? 1.f / sv : 0.f; }
    __syncthreads();
    int row = blockIdx.x;
    int beg = offs[row], end = offs[row + 1];
    int c0 = tid * 2;            // two output channels per lane
    int h = c0 >> 4;             // head for both channels
    float ax = 0.f, ay = 0.f;
    int j = beg;
    for (; j + 1 < end; j += 2) {
        int m0 = cstp[j], m1 = cstp[j + 1];
        int col0 = m0 & 0xFFFFF, col1 = m1 & 0xFFFFF;
        float a0 = scores_s[j * H_ + h] * sinv[(m0 >> 20) * H_ + h];
        float a1 = scores_s[(j + 1) * H_ + h] * sinv[(m1 >> 20) * H_ + h];
        unsigned int p0 = *(const unsigned int*)(v_bf + (size_t)col0 * C_ + c0);
        unsigned int p1 = *(const unsigned int*)(v_bf + (size_t)col1 * C_ + c0);
        ax += bf2f((unsigned short)p0) * a0 + bf2f((unsigned short)p1) * a1;
        ay += bf2f((unsigned short)(p0 >> 16)) * a0 + bf2f((unsigned short)(p1 >> 16)) * a1;
    }
    if (j < end) {
        int m0 = cstp[j];
        int col0 = m0 & 0xFFFFF;
        float a0 = scores_s[j * H_ + h] * sinv[(m0 >> 20) * H_ + h];
        unsigned int p0 = *(const unsigned int*)(v_bf + (size_t)col0 * C_ + c0);
        ax += bf2f((unsigned short)p0) * a0;
        ay += bf2f((unsigned short)(p0 >> 16)) * a0;
    }
    *(float2*)(outacc + (size_t)row * C_ + c0) = make_float2(ax, ay);
}

extern "C" void kernel_launch(void* const* d_in, const int* in_sizes, int n_in,
                              void* d_out, int out_size, void* d_ws, size_t ws_size,
                              hipStream_t stream) {
    const float* x  = (const float*)d_in[0];
    const int*   ei = (const int*)d_in[1];
    const int*   et = (const int*)d_in[2];
    // d_in[3] = num_relations (scalar) — R_ hardcoded to 5 per problem setup
    const float* Wq = (const float*)d_in[4];
    const float* bq = (const float*)d_in[5];
    const float* Wk = (const float*)d_in[6];
    const float* bk = (const float*)d_in[7];
    const float* Wv = (const float*)d_in[8];
    const float* bv = (const float*)d_in[9];
    const float* sa = (const float*)d_in[10];
    const float* Wo = (const float*)d_in[11];
    const float* bo = (const float*)d_in[12];
    float* out = (float*)d_out;

    int N = in_sizes[0] / C_;
    int E = in_sizes[2];

    float* ws = (float*)d_ws;
    float* q        = ws;                       // N*128 f32; reused as outacc
    float* k        = q + (size_t)N * C_;       // N*128 f32
    unsigned short* v_bf = (unsigned short*)(k + (size_t)N * C_);   // N*128 bf16
    float* scores_s = (float*)(v_bf + (size_t)N * C_);              // E*8 f32
    float* s        = scores_s + (size_t)E * H_;
    float* alpha    = s + RH;
    int*   cnt      = (int*)(alpha + C_);       // N ints (histogram -> cursor)
    int*   offs     = cnt + N;                  // N+1 ints
    int*   row_s    = offs + N + 1;             // E ints (row per sorted edge)
    int*   cstp     = row_s + E;                // E ints (col | type<<20)
    unsigned short* w3 = (unsigned short*)(cstp + E);  // 3*16384 bf16
    unsigned short* wo = w3 + 3 * 16384;               // 16384 bf16
    float* outacc = q;                          // alias: q dead after scores_exp
    size_t need = (size_t)((char*)(wo + 16384) - (char*)d_ws);
    if (ws_size < need) return;   // workspace too small — fail cleanly

    // ---- prep: weights to bf16, CSR build (independent of GEMMs) ----
    (void)hipMemsetAsync(cnt, 0, (size_t)N * sizeof(int), stream);
    init_kernel<<<1, 64, 0, stream>>>(sa, s, alpha);
    wprep_kernel<<<64, 256, 0, stream>>>(Wq, Wk, Wv, Wo, w3, wo);
    hist_kernel<<<(E + 255) / 256, 256, 0, stream>>>(ei, cnt, E);
    scan_kernel<<<1, 1024, 0, stream>>>(cnt, offs, N);
    fill_kernel<<<(E + 255) / 256, 256, 0, stream>>>(ei, et, cnt, row_s, cstp, E);

    // ---- main pipeline ----
    int nrt = (N + 63) / 64;
    qkv_mfma<<<nrt * 3, 256, 0, stream>>>(x, w3, bq, bk, bv, q, k, v_bf, N);
    scores_exp_kernel<<<2048, 256, 0, stream>>>(q, k, row_s, cstp, scores_s, s, E);
    gather_kernel<<<N, 64, 0, stream>>>(scores_s, v_bf, cstp, s, offs, outacc);
    ogemm_mfma<<<nrt, 256, 0, stream>>>(outacc, alpha, wo, bo, out, N);
}

// Round 7
// 307.465 us; speedup vs baseline: 23.9092x; 1.3172x over previous
//
#include <hip/hip_runtime.h>

constexpr int R_ = 5, H_ = 8, D_ = 16, C_ = 128;
constexpr int RH = R_ * H_;   // 40 softmax slots

typedef short bf16x8 __attribute__((ext_vector_type(8)));
typedef float f32x4 __attribute__((ext_vector_type(4)));

__device__ __forceinline__ unsigned short f2bf(float f) {
    unsigned int u = __float_as_uint(f);
    u += 0x7FFFu + ((u >> 16) & 1u);   // round-to-nearest-even
    return (unsigned short)(u >> 16);
}
__device__ __forceinline__ float bf2f(unsigned short b) {
    return __uint_as_float((unsigned int)b << 16);
}

// ---- init: s = 0, alpha = softmax(semantic_att, axis=0) ----
__global__ void init_kernel(const float* __restrict__ sa,
                            float* __restrict__ s, float* __restrict__ alpha) {
    int t = threadIdx.x;
    if (t < RH) s[t] = 0.0f;
    if (t < D_) {
        float vals[H_];
        float mx = -1e30f;
        #pragma unroll
        for (int h = 0; h < H_; ++h) { vals[h] = sa[h * D_ + t]; mx = fmaxf(mx, vals[h]); }
        float sum = 0.0f;
        #pragma unroll
        for (int h = 0; h < H_; ++h) { vals[h] = expf(vals[h] - mx); sum += vals[h]; }
        float inv = 1.0f / sum;
        #pragma unroll
        for (int h = 0; h < H_; ++h) alpha[h * D_ + t] = vals[h] * inv;
    }
}

// ---- convert Wq/Wk/Wv/Wo to bf16 once ----
__global__ __launch_bounds__(256) void wprep_kernel(const float* __restrict__ Wq,
                                                    const float* __restrict__ Wk,
                                                    const float* __restrict__ Wv,
                                                    const float* __restrict__ Wo,
                                                    unsigned short* __restrict__ w3,
                                                    unsigned short* __restrict__ wo) {
    int i = blockIdx.x * 256 + threadIdx.x;
    if (i < 16384) {
        w3[i]           = f2bf(Wq[i]);
        w3[16384 + i]   = f2bf(Wk[i]);
        w3[32768 + i]   = f2bf(Wv[i]);
        wo[i]           = f2bf(Wo[i]);
    }
}

// ---- CSR build: histogram of destination rows ----
__global__ __launch_bounds__(256) void hist_kernel(const int* __restrict__ ei,
                                                   int* __restrict__ cnt, int E) {
    int i = blockIdx.x * 256 + threadIdx.x;
    if (i < E) atomicAdd(&cnt[ei[i]], 1);
}

// ==== 3-phase parallel exclusive scan over N counts (block = 4096 items) ====
// phase 1: per-block totals
__global__ __launch_bounds__(1024) void scan_bsum_kernel(const int* __restrict__ cnt,
                                                         int* __restrict__ bsum, int N) {
    __shared__ int ts[1024];
    int base = blockIdx.x * 4096;
    int t = threadIdx.x;
    int i0 = base + t * 4;
    int sum = 0;
    if (i0 + 3 < N) {
        int4 vv = *(const int4*)(cnt + i0);
        sum = vv.x + vv.y + vv.z + vv.w;
    } else {
        for (int u = 0; u < 4; ++u) if (i0 + u < N) sum += cnt[i0 + u];
    }
    ts[t] = sum;
    __syncthreads();
    for (int d = 512; d > 0; d >>= 1) {
        if (t < d) ts[t] += ts[t + d];
        __syncthreads();
    }
    if (t == 0) bsum[blockIdx.x] = ts[0];
}

// phase 2: exclusive scan of block sums (single wave, carry over 64-chunks)
__global__ __launch_bounds__(64) void scan_bbase_kernel(const int* __restrict__ bsum,
                                                        int* __restrict__ bbase,
                                                        int* __restrict__ offs,
                                                        int nb, int N) {
    int l = threadIdx.x;
    int carry = 0;
    for (int b0 = 0; b0 < nb; b0 += 64) {
        int idx = b0 + l;
        int orig = (idx < nb) ? bsum[idx] : 0;
        int v = orig;
        #pragma unroll
        for (int d = 1; d < 64; d <<= 1) {
            int u = __shfl_up(v, d);
            if (l >= d) v += u;
        }
        if (idx < nb) bbase[idx] = carry + v - orig;
        carry += __shfl(v, 63);
    }
    if (l == 0) offs[N] = carry;
}

// phase 3: block-local scan + add block base; write offs + cursor init
__global__ __launch_bounds__(1024) void scan_local_kernel(int* __restrict__ cnt,
                                                          int* __restrict__ offs,
                                                          const int* __restrict__ bbase,
                                                          int N) {
    __shared__ int ts[1024];
    int base = blockIdx.x * 4096;
    int t = threadIdx.x;
    int i0 = base + t * 4;
    int v0 = 0, v1 = 0, v2 = 0, v3 = 0;
    if (i0 + 3 < N) {
        int4 vv = *(const int4*)(cnt + i0);
        v0 = vv.x; v1 = vv.y; v2 = vv.z; v3 = vv.w;
    } else {
        if (i0 + 0 < N) v0 = cnt[i0 + 0];
        if (i0 + 1 < N) v1 = cnt[i0 + 1];
        if (i0 + 2 < N) v2 = cnt[i0 + 2];
        if (i0 + 3 < N) v3 = cnt[i0 + 3];
    }
    ts[t] = v0 + v1 + v2 + v3;
    __syncthreads();
    for (int d = 1; d < 1024; d <<= 1) {           // Hillis-Steele inclusive
        int val = (t >= d) ? ts[t - d] : 0;
        __syncthreads();
        ts[t] += val;
        __syncthreads();
    }
    int e = bbase[blockIdx.x] + (t ? ts[t - 1] : 0);
    if (i0 + 0 < N) { offs[i0 + 0] = e; cnt[i0 + 0] = e; } e += v0;
    if (i0 + 1 < N) { offs[i0 + 1] = e; cnt[i0 + 1] = e; } e += v1;
    if (i0 + 2 < N) { offs[i0 + 2] = e; cnt[i0 + 2] = e; } e += v2;
    if (i0 + 3 < N) { offs[i0 + 3] = e; cnt[i0 + 3] = e; }
}

// ---- CSR build: emit row-sorted edge metadata (row, col|type packed) ----
__global__ __launch_bounds__(256) void fill_kernel(const int* __restrict__ ei,
                                                   const int* __restrict__ et,
                                                   int* __restrict__ cursor,
                                                   int* __restrict__ row_s,
                                                   int* __restrict__ cstp, int E) {
    int i = blockIdx.x * 256 + threadIdx.x;
    if (i < E) {
        int row = ei[i];
        int pos = atomicAdd(&cursor[row], 1);
        row_s[pos] = row;
        cstp[pos] = ei[E + i] | (et[i] << 20);
    }
}

// ============ MFMA GEMM: 64-row tile, 4 waves, wave = 16 rows x 128 cols ============
// LDS tile As[64][128] bf16, XOR-swizzled: byte ^= (row&7)<<4 (T2, conflict-free
// 16-lane row-strided ds_read_b128). B fragments live in registers from L2.

// stage 64x128 fp32 rows -> bf16 swizzled LDS (optionally scaled per-channel)
__device__ __forceinline__ void stage_tile(unsigned short* As, const float* __restrict__ src,
                                           const float* __restrict__ scale, int row0, int N) {
    int tid = threadIdx.x;
    #pragma unroll
    for (int it = 0; it < 4; ++it) {
        int g = tid + it * 256;       // 1024 groups of 8 bf16 (16B)
        int row = g >> 4, kg = g & 15;
        int grow = row0 + row;
        float4 f0 = make_float4(0.f, 0.f, 0.f, 0.f), f1 = f0;
        if (grow < N) {
            const float* p = src + (size_t)grow * C_ + kg * 8;
            f0 = *(const float4*)p;
            f1 = *(const float4*)(p + 4);
            if (scale) {
                float4 a0 = *(const float4*)(scale + kg * 8);
                float4 a1 = *(const float4*)(scale + kg * 8 + 4);
                f0.x *= a0.x; f0.y *= a0.y; f0.z *= a0.z; f0.w *= a0.w;
                f1.x *= a1.x; f1.y *= a1.y; f1.z *= a1.z; f1.w *= a1.w;
            }
        }
        uint4 pk;
        pk.x = f2bf(f0.x) | ((unsigned int)f2bf(f0.y) << 16);
        pk.y = f2bf(f0.z) | ((unsigned int)f2bf(f0.w) << 16);
        pk.z = f2bf(f1.x) | ((unsigned int)f2bf(f1.y) << 16);
        pk.w = f2bf(f1.z) | ((unsigned int)f2bf(f1.w) << 16);
        *(uint4*)((char*)As + (row * 256 + ((kg * 16) ^ ((row & 7) << 4)))) = pk;
    }
}

// wave GEMM body: acc[n] over 8 col-tiles; A from LDS, B frags from global bf16 W
template <bool BF_OUT>
__device__ __forceinline__ void wave_gemm(const unsigned short* As,
                                          const unsigned short* __restrict__ W,
                                          const float* __restrict__ bias,
                                          float* __restrict__ outf,
                                          unsigned short* __restrict__ outb,
                                          int row0, int N) {
    int tid = threadIdx.x;
    int l = tid & 63, wave = tid >> 6;
    int lr = l & 15, lk = (l >> 4) * 8;
    bf16x8 bfr[8][4];
    #pragma unroll
    for (int n = 0; n < 8; ++n)
        #pragma unroll
        for (int kk = 0; kk < 4; ++kk)
            bfr[n][kk] = *(const bf16x8*)(W + (n * 16 + lr) * C_ + kk * 32 + lk);
    f32x4 acc[8];
    #pragma unroll
    for (int n = 0; n < 8; ++n) acc[n] = (f32x4){0.f, 0.f, 0.f, 0.f};
    int rowA = wave * 16 + lr;
    const char* abase = (const char*)As + rowA * 256;
    int sw = (rowA & 7) << 4;
    #pragma unroll
    for (int kk = 0; kk < 4; ++kk) {
        bf16x8 a = *(const bf16x8*)(abase + (((kk * 32 + lk) * 2) ^ sw));
        #pragma unroll
        for (int n = 0; n < 8; ++n)
            acc[n] = __builtin_amdgcn_mfma_f32_16x16x32_bf16(a, bfr[n][kk], acc[n], 0, 0, 0);
    }
    // C/D: col = lane&15, row = (lane>>4)*4 + reg   [m89]
    int rbase = row0 + wave * 16 + (l >> 4) * 4;
    #pragma unroll
    for (int n = 0; n < 8; ++n) {
        int col = n * 16 + lr;
        float bc = bias[col];
        #pragma unroll
        for (int r = 0; r < 4; ++r) {
            int grow = rbase + r;
            if (grow < N) {
                float val = acc[n][r] + bc;
                if (BF_OUT) outb[(size_t)grow * C_ + col] = f2bf(val);
                else        outf[(size_t)grow * C_ + col] = val;
            }
        }
    }
}

// qkv: grid = nrt*3, rt-major (3 weight variants of a tile adjacent for x reuse)
__global__ __launch_bounds__(256) void qkv_mfma(const float* __restrict__ x,
                                                const unsigned short* __restrict__ w3,
                                                const float* __restrict__ bq,
                                                const float* __restrict__ bk,
                                                const float* __restrict__ bv,
                                                float* __restrict__ q, float* __restrict__ k,
                                                unsigned short* __restrict__ v_bf, int N) {
    __shared__ unsigned short As[64 * 128];
    int bid = blockIdx.x;
    int rt = bid / 3, wsel = bid - rt * 3;
    int row0 = rt * 64;
    const unsigned short* W = w3 + wsel * 16384;
    stage_tile(As, x, nullptr, row0, N);
    __syncthreads();
    if (wsel == 0)      wave_gemm<false>(As, W, bq, q, nullptr, row0, N);
    else if (wsel == 1) wave_gemm<false>(As, W, bk, k, nullptr, row0, N);
    else                wave_gemm<true>(As, W, bv, nullptr, v_bf, row0, N);
}

// final GEMM: out = (outacc * alpha) @ Wo^T + bo
__global__ __launch_bounds__(256) void ogemm_mfma(const float* __restrict__ outacc,
                                                  const float* __restrict__ alpha,
                                                  const unsigned short* __restrict__ wo,
                                                  const float* __restrict__ bo,
                                                  float* __restrict__ out, int N) {
    __shared__ unsigned short As[64 * 128];
    int row0 = blockIdx.x * 64;
    stage_tile(As, outacc, alpha, row0, N);
    __syncthreads();
    wave_gemm<false>(As, wo, bo, out, nullptr, row0, N);
}

// ---- fused: scores_s[j] = exp(q[row_s[j]]·k[col]/4), row-sorted order,
//      + segment sum over (relation, head). q-side is L1-local (sorted runs). ----
__global__ __launch_bounds__(256) void scores_exp_kernel(const float* __restrict__ q,
                                                         const float* __restrict__ k,
                                                         const int* __restrict__ row_s,
                                                         const int* __restrict__ cstp,
                                                         float* __restrict__ scores_s,
                                                         float* __restrict__ s, int E) {
    __shared__ float lsum[RH];
    int tid = threadIdx.x;
    if (tid < RH) lsum[tid] = 0.f;
    __syncthreads();
    int total = E * H_;
    int stride = gridDim.x * 256;
    for (int i = blockIdx.x * 256 + tid; i < total; i += stride) {
        int j = i >> 3, h = i & 7;
        int row = row_s[j];
        int m = cstp[j];
        int col = m & 0xFFFFF, t = m >> 20;
        const float4* qp = (const float4*)(q + (size_t)row * C_ + h * D_);
        const float4* kp = (const float4*)(k + (size_t)col * C_ + h * D_);
        float acc = 0.f;
        #pragma unroll
        for (int jj = 0; jj < 4; ++jj) {
            float4 a = qp[jj], b = kp[jj];
            acc += a.x * b.x + a.y * b.y + a.z * b.z + a.w * b.w;
        }
        float val = __expf(acc * 0.25f);    // 1/sqrt(16)
        scores_s[i] = val;
        atomicAdd(&lsum[t * H_ + h], val);
    }
    __syncthreads();
    if (tid < RH) atomicAdd(&s[tid], lsum[tid]);
}

// ---- gather: out[row] = sum over row's edges of attn * v[col]; scores contiguous ----
__global__ __launch_bounds__(64) void gather_kernel(const float* __restrict__ scores_s,
                                                    const unsigned short* __restrict__ v_bf,
                                                    const int* __restrict__ cstp,
                                                    const float* __restrict__ s,
                                                    const int* __restrict__ offs,
                                                    float* __restrict__ outacc) {
    __shared__ float sinv[RH];
    int tid = threadIdx.x;
    if (tid < RH) { float sv = s[tid]; sinv[tid] = sv > 0.f ? 1.f / sv : 0.f; }
    __syncthreads();
    int row = blockIdx.x;
    int beg = offs[row], end = offs[row + 1];
    int c0 = tid * 2;            // two output channels per lane
    int h = c0 >> 4;             // head for both channels
    float ax = 0.f, ay = 0.f;
    int j = beg;
    for (; j + 1 < end; j += 2) {
        int m0 = cstp[j], m1 = cstp[j + 1];
        int col0 = m0 & 0xFFFFF, col1 = m1 & 0xFFFFF;
        float a0 = scores_s[j * H_ + h] * sinv[(m0 >> 20) * H_ + h];
        float a1 = scores_s[(j + 1) * H_ + h] * sinv[(m1 >> 20) * H_ + h];
        unsigned int p0 = *(const unsigned int*)(v_bf + (size_t)col0 * C_ + c0);
        unsigned int p1 = *(const unsigned int*)(v_bf + (size_t)col1 * C_ + c0);
        ax += bf2f((unsigned short)p0) * a0 + bf2f((unsigned short)p1) * a1;
        ay += bf2f((unsigned short)(p0 >> 16)) * a0 + bf2f((unsigned short)(p1 >> 16)) * a1;
    }
    if (j < end) {
        int m0 = cstp[j];
        int col0 = m0 & 0xFFFFF;
        float a0 = scores_s[j * H_ + h] * sinv[(m0 >> 20) * H_ + h];
        unsigned int p0 = *(const unsigned int*)(v_bf + (size_t)col0 * C_ + c0);
        ax += bf2f((unsigned short)p0) * a0;
        ay += bf2f((unsigned short)(p0 >> 16)) * a0;
    }
    *(float2*)(outacc + (size_t)row * C_ + c0) = make_float2(ax, ay);
}

extern "C" void kernel_launch(void* const* d_in, const int* in_sizes, int n_in,
                              void* d_out, int out_size, void* d_ws, size_t ws_size,
                              hipStream_t stream) {
    const float* x  = (const float*)d_in[0];
    const int*   ei = (const int*)d_in[1];
    const int*   et = (const int*)d_in[2];
    // d_in[3] = num_relations (scalar) — R_ hardcoded to 5 per problem setup
    const float* Wq = (const float*)d_in[4];
    const float* bq = (const float*)d_in[5];
    const float* Wk = (const float*)d_in[6];
    const float* bk = (const float*)d_in[7];
    const float* Wv = (const float*)d_in[8];
    const float* bv = (const float*)d_in[9];
    const float* sa = (const float*)d_in[10];
    const float* Wo = (const float*)d_in[11];
    const float* bo = (const float*)d_in[12];
    float* out = (float*)d_out;

    int N = in_sizes[0] / C_;
    int E = in_sizes[2];

    float* ws = (float*)d_ws;
    float* q        = ws;                       // N*128 f32; reused as outacc
    float* k        = q + (size_t)N * C_;       // N*128 f32
    unsigned short* v_bf = (unsigned short*)(k + (size_t)N * C_);   // N*128 bf16
    float* scores_s = (float*)(v_bf + (size_t)N * C_);              // E*8 f32
    float* s        = scores_s + (size_t)E * H_;
    float* alpha    = s + RH;
    int*   cnt      = (int*)(alpha + C_);       // N ints (histogram -> cursor)
    int*   offs     = cnt + N;                  // N+1 ints
    int*   row_s    = offs + N + 1;             // E ints (row per sorted edge)
    int*   cstp     = row_s + E;                // E ints (col | type<<20)
    unsigned short* w3 = (unsigned short*)(cstp + E);  // 3*16384 bf16
    unsigned short* wo = w3 + 3 * 16384;               // 16384 bf16
    int*   bsum    = (int*)(wo + 16384);        // scan block sums (nb)
    int*   bbase   = bsum + 1024;               // scan block bases (nb)
    float* outacc = q;                          // alias: q dead after scores_exp
    size_t need = (size_t)((char*)(bbase + 1024) - (char*)d_ws);
    if (ws_size < need) return;   // workspace too small — fail cleanly

    // ---- prep: weights to bf16, CSR build (independent of GEMMs) ----
    (void)hipMemsetAsync(cnt, 0, (size_t)N * sizeof(int), stream);
    init_kernel<<<1, 64, 0, stream>>>(sa, s, alpha);
    wprep_kernel<<<64, 256, 0, stream>>>(Wq, Wk, Wv, Wo, w3, wo);
    hist_kernel<<<(E + 255) / 256, 256, 0, stream>>>(ei, cnt, E);
    int nb = (N + 4095) / 4096;
    scan_bsum_kernel<<<nb, 1024, 0, stream>>>(cnt, bsum, N);
    scan_bbase_kernel<<<1, 64, 0, stream>>>(bsum, bbase, offs, nb, N);
    scan_local_kernel<<<nb, 1024, 0, stream>>>(cnt, offs, bbase, N);
    fill_kernel<<<(E + 255) / 256, 256, 0, stream>>>(ei, et, cnt, row_s, cstp, E);

    // ---- main pipeline ----
    int nrt = (N + 63) / 64;
    qkv_mfma<<<nrt * 3, 256, 0, stream>>>(x, w3, bq, bk, bv, q, k, v_bf, N);
    scores_exp_kernel<<<2048, 256, 0, stream>>>(q, k, row_s, cstp, scores_s, s, E);
    gather_kernel<<<N, 64, 0, stream>>>(scores_s, v_bf, cstp, s, offs, outacc);
    ogemm_mfma<<<nrt, 256, 0, stream>>>(outacc, alpha, wo, bo, out, N);
}

// Round 8
// 302.158 us; speedup vs baseline: 24.3291x; 1.0176x over previous
//
#include <hip/hip_runtime.h>

constexpr int R_ = 5, H_ = 8, D_ = 16, C_ = 128;
constexpr int RH = R_ * H_;   // 40 softmax slots

typedef short bf16x8 __attribute__((ext_vector_type(8)));
typedef float f32x4 __attribute__((ext_vector_type(4)));

__device__ __forceinline__ unsigned short f2bf(float f) {
    unsigned int u = __float_as_uint(f);
    u += 0x7FFFu + ((u >> 16) & 1u);   // round-to-nearest-even
    return (unsigned short)(u >> 16);
}
__device__ __forceinline__ float bf2f(unsigned short b) {
    return __uint_as_float((unsigned int)b << 16);
}
// dot of 8 bf16 pairs packed in uint4
__device__ __forceinline__ float dot8(uint4 a, uint4 b) {
    const unsigned int* pa = (const unsigned int*)&a;
    const unsigned int* pb = (const unsigned int*)&b;
    float s = 0.f;
    #pragma unroll
    for (int u = 0; u < 4; ++u) {
        s += bf2f((unsigned short)pa[u]) * bf2f((unsigned short)pb[u]);
        s += bf2f((unsigned short)(pa[u] >> 16)) * bf2f((unsigned short)(pb[u] >> 16));
    }
    return s;
}

// ---- init: s = 0, alpha = softmax(semantic_att, axis=0) ----
__global__ void init_kernel(const float* __restrict__ sa,
                            float* __restrict__ s, float* __restrict__ alpha) {
    int t = threadIdx.x;
    if (t < RH) s[t] = 0.0f;
    if (t < D_) {
        float vals[H_];
        float mx = -1e30f;
        #pragma unroll
        for (int h = 0; h < H_; ++h) { vals[h] = sa[h * D_ + t]; mx = fmaxf(mx, vals[h]); }
        float sum = 0.0f;
        #pragma unroll
        for (int h = 0; h < H_; ++h) { vals[h] = expf(vals[h] - mx); sum += vals[h]; }
        float inv = 1.0f / sum;
        #pragma unroll
        for (int h = 0; h < H_; ++h) alpha[h * D_ + t] = vals[h] * inv;
    }
}

// ---- convert Wq/Wk/Wv/Wo to bf16 once ----
__global__ __launch_bounds__(256) void wprep_kernel(const float* __restrict__ Wq,
                                                    const float* __restrict__ Wk,
                                                    const float* __restrict__ Wv,
                                                    const float* __restrict__ Wo,
                                                    unsigned short* __restrict__ w3,
                                                    unsigned short* __restrict__ wo) {
    int i = blockIdx.x * 256 + threadIdx.x;
    if (i < 16384) {
        w3[i]           = f2bf(Wq[i]);
        w3[16384 + i]   = f2bf(Wk[i]);
        w3[32768 + i]   = f2bf(Wv[i]);
        wo[i]           = f2bf(Wo[i]);
    }
}

// ---- CSR build: histogram of destination rows ----
__global__ __launch_bounds__(256) void hist_kernel(const int* __restrict__ ei,
                                                   int* __restrict__ cnt, int E) {
    int i = blockIdx.x * 256 + threadIdx.x;
    if (i < E) atomicAdd(&cnt[ei[i]], 1);
}

// ==== 3-phase parallel exclusive scan over N counts (block = 4096 items) ====
__global__ __launch_bounds__(1024) void scan_bsum_kernel(const int* __restrict__ cnt,
                                                         int* __restrict__ bsum, int N) {
    __shared__ int ts[1024];
    int base = blockIdx.x * 4096;
    int t = threadIdx.x;
    int i0 = base + t * 4;
    int sum = 0;
    if (i0 + 3 < N) {
        int4 vv = *(const int4*)(cnt + i0);
        sum = vv.x + vv.y + vv.z + vv.w;
    } else {
        for (int u = 0; u < 4; ++u) if (i0 + u < N) sum += cnt[i0 + u];
    }
    ts[t] = sum;
    __syncthreads();
    for (int d = 512; d > 0; d >>= 1) {
        if (t < d) ts[t] += ts[t + d];
        __syncthreads();
    }
    if (t == 0) bsum[blockIdx.x] = ts[0];
}

__global__ __launch_bounds__(64) void scan_bbase_kernel(const int* __restrict__ bsum,
                                                        int* __restrict__ bbase,
                                                        int* __restrict__ offs,
                                                        int nb, int N) {
    int l = threadIdx.x;
    int carry = 0;
    for (int b0 = 0; b0 < nb; b0 += 64) {
        int idx = b0 + l;
        int orig = (idx < nb) ? bsum[idx] : 0;
        int v = orig;
        #pragma unroll
        for (int d = 1; d < 64; d <<= 1) {
            int u = __shfl_up(v, d);
            if (l >= d) v += u;
        }
        if (idx < nb) bbase[idx] = carry + v - orig;
        carry += __shfl(v, 63);
    }
    if (l == 0) offs[N] = carry;
}

__global__ __launch_bounds__(1024) void scan_local_kernel(int* __restrict__ cnt,
                                                          int* __restrict__ offs,
                                                          const int* __restrict__ bbase,
                                                          int N) {
    __shared__ int ts[1024];
    int base = blockIdx.x * 4096;
    int t = threadIdx.x;
    int i0 = base + t * 4;
    int v0 = 0, v1 = 0, v2 = 0, v3 = 0;
    if (i0 + 3 < N) {
        int4 vv = *(const int4*)(cnt + i0);
        v0 = vv.x; v1 = vv.y; v2 = vv.z; v3 = vv.w;
    } else {
        if (i0 + 0 < N) v0 = cnt[i0 + 0];
        if (i0 + 1 < N) v1 = cnt[i0 + 1];
        if (i0 + 2 < N) v2 = cnt[i0 + 2];
        if (i0 + 3 < N) v3 = cnt[i0 + 3];
    }
    ts[t] = v0 + v1 + v2 + v3;
    __syncthreads();
    for (int d = 1; d < 1024; d <<= 1) {           // Hillis-Steele inclusive
        int val = (t >= d) ? ts[t - d] : 0;
        __syncthreads();
        ts[t] += val;
        __syncthreads();
    }
    int e = bbase[blockIdx.x] + (t ? ts[t - 1] : 0);
    if (i0 + 0 < N) { offs[i0 + 0] = e; cnt[i0 + 0] = e; } e += v0;
    if (i0 + 1 < N) { offs[i0 + 1] = e; cnt[i0 + 1] = e; } e += v1;
    if (i0 + 2 < N) { offs[i0 + 2] = e; cnt[i0 + 2] = e; } e += v2;
    if (i0 + 3 < N) { offs[i0 + 3] = e; cnt[i0 + 3] = e; }
}

// ---- CSR build: emit row-sorted packed edge metadata (row, col|type<<20) ----
__global__ __launch_bounds__(256) void fill_kernel(const int* __restrict__ ei,
                                                   const int* __restrict__ et,
                                                   int* __restrict__ cursor,
                                                   int2* __restrict__ em, int E) {
    int i = blockIdx.x * 256 + threadIdx.x;
    if (i < E) {
        int row = ei[i];
        int pos = atomicAdd(&cursor[row], 1);
        em[pos] = make_int2(row, ei[E + i] | (et[i] << 20));
    }
}

// ============ MFMA GEMM: 64-row tile, 4 waves, wave = 16 rows x 128 cols ============
// LDS tile As[64][128] bf16, XOR-swizzled: byte ^= (row&7)<<4 (T2, conflict-free
// 16-lane row-strided ds_read_b128). B fragments live in registers from L2.

// stage 64x128 fp32 rows -> bf16 swizzled LDS (optionally scaled per-channel)
__device__ __forceinline__ void stage_tile(unsigned short* As, const float* __restrict__ src,
                                           const float* __restrict__ scale, int row0, int N) {
    int tid = threadIdx.x;
    #pragma unroll
    for (int it = 0; it < 4; ++it) {
        int g = tid + it * 256;       // 1024 groups of 8 bf16 (16B)
        int row = g >> 4, kg = g & 15;
        int grow = row0 + row;
        float4 f0 = make_float4(0.f, 0.f, 0.f, 0.f), f1 = f0;
        if (grow < N) {
            const float* p = src + (size_t)grow * C_ + kg * 8;
            f0 = *(const float4*)p;
            f1 = *(const float4*)(p + 4);
            if (scale) {
                float4 a0 = *(const float4*)(scale + kg * 8);
                float4 a1 = *(const float4*)(scale + kg * 8 + 4);
                f0.x *= a0.x; f0.y *= a0.y; f0.z *= a0.z; f0.w *= a0.w;
                f1.x *= a1.x; f1.y *= a1.y; f1.z *= a1.z; f1.w *= a1.w;
            }
        }
        uint4 pk;
        pk.x = f2bf(f0.x) | ((unsigned int)f2bf(f0.y) << 16);
        pk.y = f2bf(f0.z) | ((unsigned int)f2bf(f0.w) << 16);
        pk.z = f2bf(f1.x) | ((unsigned int)f2bf(f1.y) << 16);
        pk.w = f2bf(f1.z) | ((unsigned int)f2bf(f1.w) << 16);
        *(uint4*)((char*)As + (row * 256 + ((kg * 16) ^ ((row & 7) << 4)))) = pk;
    }
}

// wave GEMM body: acc[n] over 8 col-tiles; A from LDS, B frags from global bf16 W
template <bool BF_OUT>
__device__ __forceinline__ void wave_gemm(const unsigned short* As,
                                          const unsigned short* __restrict__ W,
                                          const float* __restrict__ bias,
                                          float* __restrict__ outf,
                                          unsigned short* __restrict__ outb,
                                          int row0, int N) {
    int tid = threadIdx.x;
    int l = tid & 63, wave = tid >> 6;
    int lr = l & 15, lk = (l >> 4) * 8;
    bf16x8 bfr[8][4];
    #pragma unroll
    for (int n = 0; n < 8; ++n)
        #pragma unroll
        for (int kk = 0; kk < 4; ++kk)
            bfr[n][kk] = *(const bf16x8*)(W + (n * 16 + lr) * C_ + kk * 32 + lk);
    f32x4 acc[8];
    #pragma unroll
    for (int n = 0; n < 8; ++n) acc[n] = (f32x4){0.f, 0.f, 0.f, 0.f};
    int rowA = wave * 16 + lr;
    const char* abase = (const char*)As + rowA * 256;
    int sw = (rowA & 7) << 4;
    #pragma unroll
    for (int kk = 0; kk < 4; ++kk) {
        bf16x8 a = *(const bf16x8*)(abase + (((kk * 32 + lk) * 2) ^ sw));
        #pragma unroll
        for (int n = 0; n < 8; ++n)
            acc[n] = __builtin_amdgcn_mfma_f32_16x16x32_bf16(a, bfr[n][kk], acc[n], 0, 0, 0);
    }
    // C/D: col = lane&15, row = (lane>>4)*4 + reg   [m89]
    int rbase = row0 + wave * 16 + (l >> 4) * 4;
    #pragma unroll
    for (int n = 0; n < 8; ++n) {
        int col = n * 16 + lr;
        float bc = bias[col];
        #pragma unroll
        for (int r = 0; r < 4; ++r) {
            int grow = rbase + r;
            if (grow < N) {
                float val = acc[n][r] + bc;
                if (BF_OUT) outb[(size_t)grow * C_ + col] = f2bf(val);
                else        outf[(size_t)grow * C_ + col] = val;
            }
        }
    }
}

// qkv: grid = nrt*3, rt-major (3 weight variants of a tile adjacent for x reuse)
__global__ __launch_bounds__(256) void qkv_mfma(const float* __restrict__ x,
                                                const unsigned short* __restrict__ w3,
                                                const float* __restrict__ bq,
                                                const float* __restrict__ bk,
                                                const float* __restrict__ bv,
                                                unsigned short* __restrict__ q_bf,
                                                unsigned short* __restrict__ k_bf,
                                                unsigned short* __restrict__ v_bf, int N) {
    __shared__ unsigned short As[64 * 128];
    int bid = blockIdx.x;
    int rt = bid / 3, wsel = bid - rt * 3;
    int row0 = rt * 64;
    const unsigned short* W = w3 + wsel * 16384;
    stage_tile(As, x, nullptr, row0, N);
    __syncthreads();
    if (wsel == 0)      wave_gemm<true>(As, W, bq, nullptr, q_bf, row0, N);
    else if (wsel == 1) wave_gemm<true>(As, W, bk, nullptr, k_bf, row0, N);
    else                wave_gemm<true>(As, W, bv, nullptr, v_bf, row0, N);
}

// final GEMM: out = (outacc * alpha) @ Wo^T + bo
__global__ __launch_bounds__(256) void ogemm_mfma(const float* __restrict__ outacc,
                                                  const float* __restrict__ alpha,
                                                  const unsigned short* __restrict__ wo,
                                                  const float* __restrict__ bo,
                                                  float* __restrict__ out, int N) {
    __shared__ unsigned short As[64 * 128];
    int row0 = blockIdx.x * 64;
    stage_tile(As, outacc, alpha, row0, N);
    __syncthreads();
    wave_gemm<false>(As, wo, bo, out, nullptr, row0, N);
}

// ---- fused: scores_s[j] = exp(q[row]·k[col]/4), row-sorted, bf16 q/k,
//      + segment sum over (relation, head). q-side is L1-local (sorted runs). ----
__global__ __launch_bounds__(256) void scores_exp_kernel(const unsigned short* __restrict__ q_bf,
                                                         const unsigned short* __restrict__ k_bf,
                                                         const int2* __restrict__ em,
                                                         float* __restrict__ scores_s,
                                                         float* __restrict__ s, int E) {
    __shared__ float lsum[RH];
    int tid = threadIdx.x;
    if (tid < RH) lsum[tid] = 0.f;
    __syncthreads();
    int total = E * H_;
    int stride = gridDim.x * 256;
    for (int i = blockIdx.x * 256 + tid; i < total; i += stride) {
        int j = i >> 3, h = i & 7;
        int2 m = em[j];
        int row = m.x;
        int col = m.y & 0xFFFFF, t = m.y >> 20;
        const uint4* qp = (const uint4*)(q_bf + (size_t)row * C_ + h * D_);
        const uint4* kp = (const uint4*)(k_bf + (size_t)col * C_ + h * D_);
        float acc = dot8(qp[0], kp[0]) + dot8(qp[1], kp[1]);
        float val = __expf(acc * 0.25f);    // 1/sqrt(16)
        scores_s[i] = val;
        atomicAdd(&lsum[t * H_ + h], val);
    }
    __syncthreads();
    if (tid < RH) atomicAdd(&s[tid], lsum[tid]);
}

// ---- gather: out[row] = sum over row's edges of attn * v[col]; scores contiguous ----
__global__ __launch_bounds__(64) void gather_kernel(const float* __restrict__ scores_s,
                                                    const unsigned short* __restrict__ v_bf,
                                                    const int2* __restrict__ em,
                                                    const float* __restrict__ s,
                                                    const int* __restrict__ offs,
                                                    float* __restrict__ outacc) {
    __shared__ float sinv[RH];
    int tid = threadIdx.x;
    if (tid < RH) { float sv = s[tid]; sinv[tid] = sv > 0.f ? 1.f / sv : 0.f; }
    __syncthreads();
    int row = blockIdx.x;
    int beg = offs[row], end = offs[row + 1];
    int c0 = tid * 2;            // two output channels per lane
    int h = c0 >> 4;             // head for both channels
    float ax = 0.f, ay = 0.f;
    int j = beg;
    for (; j + 1 < end; j += 2) {
        int m0 = em[j].y, m1 = em[j + 1].y;
        int col0 = m0 & 0xFFFFF, col1 = m1 & 0xFFFFF;
        float a0 = scores_s[j * H_ + h] * sinv[(m0 >> 20) * H_ + h];
        float a1 = scores_s[(j + 1) * H_ + h] * sinv[(m1 >> 20) * H_ + h];
        unsigned int p0 = *(const unsigned int*)(v_bf + (size_t)col0 * C_ + c0);
        unsigned int p1 = *(const unsigned int*)(v_bf + (size_t)col1 * C_ + c0);
        ax += bf2f((unsigned short)p0) * a0 + bf2f((unsigned short)p1) * a1;
        ay += bf2f((unsigned short)(p0 >> 16)) * a0 + bf2f((unsigned short)(p1 >> 16)) * a1;
    }
    if (j < end) {
        int m0 = em[j].y;
        int col0 = m0 & 0xFFFFF;
        float a0 = scores_s[j * H_ + h] * sinv[(m0 >> 20) * H_ + h];
        unsigned int p0 = *(const unsigned int*)(v_bf + (size_t)col0 * C_ + c0);
        ax += bf2f((unsigned short)p0) * a0;
        ay += bf2f((unsigned short)(p0 >> 16)) * a0;
    }
    *(float2*)(outacc + (size_t)row * C_ + c0) = make_float2(ax, ay);
}

extern "C" void kernel_launch(void* const* d_in, const int* in_sizes, int n_in,
                              void* d_out, int out_size, void* d_ws, size_t ws_size,
                              hipStream_t stream) {
    const float* x  = (const float*)d_in[0];
    const int*   ei = (const int*)d_in[1];
    const int*   et = (const int*)d_in[2];
    // d_in[3] = num_relations (scalar) — R_ hardcoded to 5 per problem setup
    const float* Wq = (const float*)d_in[4];
    const float* bq = (const float*)d_in[5];
    const float* Wk = (const float*)d_in[6];
    const float* bk = (const float*)d_in[7];
    const float* Wv = (const float*)d_in[8];
    const float* bv = (const float*)d_in[9];
    const float* sa = (const float*)d_in[10];
    const float* Wo = (const float*)d_in[11];
    const float* bo = (const float*)d_in[12];
    float* out = (float*)d_out;

    int N = in_sizes[0] / C_;
    int E = in_sizes[2];

    // layout (all sections 8B-aligned for int2/uint4 access):
    unsigned short* q_bf = (unsigned short*)d_ws;          // N*C bf16
    unsigned short* k_bf = q_bf + (size_t)N * C_;          // N*C bf16
    unsigned short* v_bf = k_bf + (size_t)N * C_;          // N*C bf16
    float* scores_s = (float*)(v_bf + (size_t)N * C_);     // E*8 f32
    float* s        = scores_s + (size_t)E * H_;           // RH
    float* alpha    = s + RH;                              // C (RH+C=168 f32, 8B-ok)
    int2*  em       = (int2*)(alpha + C_);                 // E int2 (row, col|type<<20)
    int*   cnt      = (int*)(em + E);                      // N ints (histogram -> cursor)
    int*   offs     = cnt + N;                             // N+1 ints
    unsigned short* w3 = (unsigned short*)(offs + N + 2);  // 3*16384 bf16 (pad to 8B)
    unsigned short* wo = w3 + 3 * 16384;                   // 16384 bf16
    int*   bsum    = (int*)(wo + 16384);                   // scan block sums
    int*   bbase   = bsum + 1024;                          // scan block bases
    float* outacc  = (float*)q_bf;   // alias: q_bf+k_bf (dead after scores) = N*C f32
    size_t need = (size_t)((char*)(bbase + 1024) - (char*)d_ws);
    if (ws_size < need) return;   // workspace too small — fail cleanly

    // ---- prep: weights to bf16, CSR build (independent of GEMMs) ----
    (void)hipMemsetAsync(cnt, 0, (size_t)N * sizeof(int), stream);
    init_kernel<<<1, 64, 0, stream>>>(sa, s, alpha);
    wprep_kernel<<<64, 256, 0, stream>>>(Wq, Wk, Wv, Wo, w3, wo);
    hist_kernel<<<(E + 255) / 256, 256, 0, stream>>>(ei, cnt, E);
    int nb = (N + 4095) / 4096;
    scan_bsum_kernel<<<nb, 1024, 0, stream>>>(cnt, bsum, N);
    scan_bbase_kernel<<<1, 64, 0, stream>>>(bsum, bbase, offs, nb, N);
    scan_local_kernel<<<nb, 1024, 0, stream>>>(cnt, offs, bbase, N);
    fill_kernel<<<(E + 255) / 256, 256, 0, stream>>>(ei, et, cnt, em, E);

    // ---- main pipeline ----
    int nrt = (N + 63) / 64;
    qkv_mfma<<<nrt * 3, 256, 0, stream>>>(x, w3, bq, bk, bv, q_bf, k_bf, v_bf, N);
    scores_exp_kernel<<<2048, 256, 0, stream>>>(q_bf, k_bf, em, scores_s, s, E);
    gather_kernel<<<N, 64, 0, stream>>>(scores_s, v_bf, em, s, offs, outacc);
    ogemm_mfma<<<nrt, 256, 0, stream>>>(outacc, alpha, wo, bo, out, N);
}

// Round 9
// 261.486 us; speedup vs baseline: 28.1132x; 1.1555x over previous
//
#include <hip/hip_runtime.h>

constexpr int R_ = 5, H_ = 8, D_ = 16, C_ = 128;
constexpr int RH = R_ * H_;   // 40 softmax slots

typedef short bf16x8 __attribute__((ext_vector_type(8)));
typedef float f32x4 __attribute__((ext_vector_type(4)));

__device__ __forceinline__ unsigned short f2bf(float f) {
    unsigned int u = __float_as_uint(f);
    u += 0x7FFFu + ((u >> 16) & 1u);   // round-to-nearest-even
    return (unsigned short)(u >> 16);
}
__device__ __forceinline__ float bf2f(unsigned short b) {
    return __uint_as_float((unsigned int)b << 16);
}
// dot of 8 bf16 pairs packed in uint4
__device__ __forceinline__ float dot8(uint4 a, uint4 b) {
    const unsigned int* pa = (const unsigned int*)&a;
    const unsigned int* pb = (const unsigned int*)&b;
    float s = 0.f;
    #pragma unroll
    for (int u = 0; u < 4; ++u) {
        s += bf2f((unsigned short)pa[u]) * bf2f((unsigned short)pb[u]);
        s += bf2f((unsigned short)(pa[u] >> 16)) * bf2f((unsigned short)(pb[u] >> 16));
    }
    return s;
}

// ---- init: s = 0, alpha = softmax(semantic_att, axis=0) ----
__global__ void init_kernel(const float* __restrict__ sa,
                            float* __restrict__ s, float* __restrict__ alpha) {
    int t = threadIdx.x;
    if (t < RH) s[t] = 0.0f;
    if (t < D_) {
        float vals[H_];
        float mx = -1e30f;
        #pragma unroll
        for (int h = 0; h < H_; ++h) { vals[h] = sa[h * D_ + t]; mx = fmaxf(mx, vals[h]); }
        float sum = 0.0f;
        #pragma unroll
        for (int h = 0; h < H_; ++h) { vals[h] = expf(vals[h] - mx); sum += vals[h]; }
        float inv = 1.0f / sum;
        #pragma unroll
        for (int h = 0; h < H_; ++h) alpha[h * D_ + t] = vals[h] * inv;
    }
}

// ---- convert Wq/Wk/Wv/Wo to bf16 once ----
__global__ __launch_bounds__(256) void wprep_kernel(const float* __restrict__ Wq,
                                                    const float* __restrict__ Wk,
                                                    const float* __restrict__ Wv,
                                                    const float* __restrict__ Wo,
                                                    unsigned short* __restrict__ w3,
                                                    unsigned short* __restrict__ wo) {
    int i = blockIdx.x * 256 + threadIdx.x;
    if (i < 16384) {
        w3[i]           = f2bf(Wq[i]);
        w3[16384 + i]   = f2bf(Wk[i]);
        w3[32768 + i]   = f2bf(Wv[i]);
        wo[i]           = f2bf(Wo[i]);
    }
}

// ---- CSR build: histogram of destination rows ----
__global__ __launch_bounds__(256) void hist_kernel(const int* __restrict__ ei,
                                                   int* __restrict__ cnt, int E) {
    int i = blockIdx.x * 256 + threadIdx.x;
    if (i < E) atomicAdd(&cnt[ei[i]], 1);
}

// ==== 3-phase parallel exclusive scan over N counts (block = 4096 items) ====
__global__ __launch_bounds__(1024) void scan_bsum_kernel(const int* __restrict__ cnt,
                                                         int* __restrict__ bsum, int N) {
    __shared__ int ts[1024];
    int base = blockIdx.x * 4096;
    int t = threadIdx.x;
    int i0 = base + t * 4;
    int sum = 0;
    if (i0 + 3 < N) {
        int4 vv = *(const int4*)(cnt + i0);
        sum = vv.x + vv.y + vv.z + vv.w;
    } else {
        for (int u = 0; u < 4; ++u) if (i0 + u < N) sum += cnt[i0 + u];
    }
    ts[t] = sum;
    __syncthreads();
    for (int d = 512; d > 0; d >>= 1) {
        if (t < d) ts[t] += ts[t + d];
        __syncthreads();
    }
    if (t == 0) bsum[blockIdx.x] = ts[0];
}

__global__ __launch_bounds__(64) void scan_bbase_kernel(const int* __restrict__ bsum,
                                                        int* __restrict__ bbase,
                                                        int* __restrict__ offs,
                                                        int nb, int N) {
    int l = threadIdx.x;
    int carry = 0;
    for (int b0 = 0; b0 < nb; b0 += 64) {
        int idx = b0 + l;
        int orig = (idx < nb) ? bsum[idx] : 0;
        int v = orig;
        #pragma unroll
        for (int d = 1; d < 64; d <<= 1) {
            int u = __shfl_up(v, d);
            if (l >= d) v += u;
        }
        if (idx < nb) bbase[idx] = carry + v - orig;
        carry += __shfl(v, 63);
    }
    if (l == 0) offs[N] = carry;
}

__global__ __launch_bounds__(1024) void scan_local_kernel(int* __restrict__ cnt,
                                                          int* __restrict__ offs,
                                                          const int* __restrict__ bbase,
                                                          int N) {
    __shared__ int ts[1024];
    int base = blockIdx.x * 4096;
    int t = threadIdx.x;
    int i0 = base + t * 4;
    int v0 = 0, v1 = 0, v2 = 0, v3 = 0;
    if (i0 + 3 < N) {
        int4 vv = *(const int4*)(cnt + i0);
        v0 = vv.x; v1 = vv.y; v2 = vv.z; v3 = vv.w;
    } else {
        if (i0 + 0 < N) v0 = cnt[i0 + 0];
        if (i0 + 1 < N) v1 = cnt[i0 + 1];
        if (i0 + 2 < N) v2 = cnt[i0 + 2];
        if (i0 + 3 < N) v3 = cnt[i0 + 3];
    }
    ts[t] = v0 + v1 + v2 + v3;
    __syncthreads();
    for (int d = 1; d < 1024; d <<= 1) {           // Hillis-Steele inclusive
        int val = (t >= d) ? ts[t - d] : 0;
        __syncthreads();
        ts[t] += val;
        __syncthreads();
    }
    int e = bbase[blockIdx.x] + (t ? ts[t - 1] : 0);
    if (i0 + 0 < N) { offs[i0 + 0] = e; cnt[i0 + 0] = e; } e += v0;
    if (i0 + 1 < N) { offs[i0 + 1] = e; cnt[i0 + 1] = e; } e += v1;
    if (i0 + 2 < N) { offs[i0 + 2] = e; cnt[i0 + 2] = e; } e += v2;
    if (i0 + 3 < N) { offs[i0 + 3] = e; cnt[i0 + 3] = e; }
}

// ---- CSR build: emit row-sorted packed edge metadata (row, col|type<<20) ----
__global__ __launch_bounds__(256) void fill_kernel(const int* __restrict__ ei,
                                                   const int* __restrict__ et,
                                                   int* __restrict__ cursor,
                                                   int2* __restrict__ em, int E) {
    int i = blockIdx.x * 256 + threadIdx.x;
    if (i < E) {
        int row = ei[i];
        int pos = atomicAdd(&cursor[row], 1);
        em[pos] = make_int2(row, ei[E + i] | (et[i] << 20));
    }
}

// ============ MFMA GEMM: 64-row tile, 4 waves; W staged in LDS, operand-swapped
// so each lane's 4 acc regs = 4 consecutive output channels (packed stores). ====
// Both LDS tiles XOR-swizzled: byte ^= (row&7)<<4 (conflict-free ds_read_b128).

// stage 64x128 fp32 rows -> bf16 swizzled LDS (optionally scaled per-channel)
__device__ __forceinline__ void stage_tile(unsigned short* As, const float* __restrict__ src,
                                           const float* __restrict__ scale, int row0, int N) {
    int tid = threadIdx.x;
    #pragma unroll
    for (int it = 0; it < 4; ++it) {
        int g = tid + it * 256;       // 1024 groups of 8 bf16 (16B)
        int row = g >> 4, kg = g & 15;
        int grow = row0 + row;
        float4 f0 = make_float4(0.f, 0.f, 0.f, 0.f), f1 = f0;
        if (grow < N) {
            const float* p = src + (size_t)grow * C_ + kg * 8;
            f0 = *(const float4*)p;
            f1 = *(const float4*)(p + 4);
            if (scale) {
                float4 a0 = *(const float4*)(scale + kg * 8);
                float4 a1 = *(const float4*)(scale + kg * 8 + 4);
                f0.x *= a0.x; f0.y *= a0.y; f0.z *= a0.z; f0.w *= a0.w;
                f1.x *= a1.x; f1.y *= a1.y; f1.z *= a1.z; f1.w *= a1.w;
            }
        }
        uint4 pk;
        pk.x = f2bf(f0.x) | ((unsigned int)f2bf(f0.y) << 16);
        pk.y = f2bf(f0.z) | ((unsigned int)f2bf(f0.w) << 16);
        pk.z = f2bf(f1.x) | ((unsigned int)f2bf(f1.y) << 16);
        pk.w = f2bf(f1.z) | ((unsigned int)f2bf(f1.w) << 16);
        *(uint4*)((char*)As + (row * 256 + ((kg * 16) ^ ((row & 7) << 4)))) = pk;
    }
}

// stage 128x128 bf16 W -> swizzled LDS (straight copy, 16B granules)
__device__ __forceinline__ void stage_w(unsigned short* Ws, const unsigned short* __restrict__ w) {
    int tid = threadIdx.x;
    const uint4* src = (const uint4*)w;   // 2048 x 16B
    #pragma unroll
    for (int it = 0; it < 8; ++it) {
        int g = tid + it * 256;
        int row = g >> 4, kg = g & 15;
        uint4 v = src[g];
        *(uint4*)((char*)Ws + (row * 256 + ((kg * 16) ^ ((row & 7) << 4)))) = v;
    }
}

// wave GEMM: acc[n] = mfma(W_frag, x_frag) -> lane holds 4 consecutive channels
template <bool BF_OUT>
__device__ __forceinline__ void wave_gemm(const unsigned short* As,
                                          const unsigned short* Ws,
                                          const float* __restrict__ bias,
                                          float* __restrict__ outf,
                                          unsigned short* __restrict__ outb,
                                          int row0, int N) {
    int tid = threadIdx.x;
    int l = tid & 63, wave = tid >> 6;
    int lr = l & 15, lk = (l >> 4) * 8;
    int rowA = wave * 16 + lr;                 // x-row (B-operand free index)
    const char* xbase = (const char*)As + rowA * 256;
    int swx = (rowA & 7) << 4;
    f32x4 acc[8];
    #pragma unroll
    for (int n = 0; n < 8; ++n) acc[n] = (f32x4){0.f, 0.f, 0.f, 0.f};
    #pragma unroll
    for (int kk = 0; kk < 4; ++kk) {
        bf16x8 xb = *(const bf16x8*)(xbase + (((kk * 32 + lk) * 2) ^ swx));
        #pragma unroll
        for (int n = 0; n < 8; ++n) {
            int ch = n * 16 + lr;              // W channel (A-operand free index)
            bf16x8 wf = *(const bf16x8*)((const char*)Ws + ch * 256 +
                                         (((kk * 32 + lk) * 2) ^ ((ch & 7) << 4)));
            acc[n] = __builtin_amdgcn_mfma_f32_16x16x32_bf16(wf, xb, acc[n], 0, 0, 0);
        }
    }
    // D: "row" = (l>>4)*4+reg -> W-channel, "col" = l&15 -> x-row   [m89 + swap]
    int xrow = row0 + wave * 16 + lr;
    int chb = (l >> 4) * 4;
    if (xrow < N) {
        #pragma unroll
        for (int n = 0; n < 8; ++n) {
            int ch = n * 16 + chb;
            float4 b4 = *(const float4*)(bias + ch);
            float v0 = acc[n][0] + b4.x, v1 = acc[n][1] + b4.y;
            float v2 = acc[n][2] + b4.z, v3 = acc[n][3] + b4.w;
            if (BF_OUT) {
                uint2 p;
                p.x = f2bf(v0) | ((unsigned int)f2bf(v1) << 16);
                p.y = f2bf(v2) | ((unsigned int)f2bf(v3) << 16);
                *(uint2*)(outb + (size_t)xrow * C_ + ch) = p;
            } else {
                *(float4*)(outf + (size_t)xrow * C_ + ch) = make_float4(v0, v1, v2, v3);
            }
        }
    }
}

// qkv: grid = nrt*3, rt-major (3 weight variants of a tile adjacent for x reuse)
__global__ __launch_bounds__(256) void qkv_mfma(const float* __restrict__ x,
                                                const unsigned short* __restrict__ w3,
                                                const float* __restrict__ bq,
                                                const float* __restrict__ bk,
                                                const float* __restrict__ bv,
                                                unsigned short* __restrict__ q_bf,
                                                unsigned short* __restrict__ k_bf,
                                                unsigned short* __restrict__ v_bf, int N) {
    __shared__ unsigned short As[64 * 128];
    __shared__ unsigned short Ws[128 * 128];
    int bid = blockIdx.x;
    int rt = bid / 3, wsel = bid - rt * 3;
    int row0 = rt * 64;
    stage_tile(As, x, nullptr, row0, N);
    stage_w(Ws, w3 + wsel * 16384);
    __syncthreads();
    if (wsel == 0)      wave_gemm<true>(As, Ws, bq, nullptr, q_bf, row0, N);
    else if (wsel == 1) wave_gemm<true>(As, Ws, bk, nullptr, k_bf, row0, N);
    else                wave_gemm<true>(As, Ws, bv, nullptr, v_bf, row0, N);
}

// final GEMM: out = (outacc * alpha) @ Wo^T + bo
__global__ __launch_bounds__(256) void ogemm_mfma(const float* __restrict__ outacc,
                                                  const float* __restrict__ alpha,
                                                  const unsigned short* __restrict__ wo,
                                                  const float* __restrict__ bo,
                                                  float* __restrict__ out, int N) {
    __shared__ unsigned short As[64 * 128];
    __shared__ unsigned short Ws[128 * 128];
    int row0 = blockIdx.x * 64;
    stage_tile(As, outacc, alpha, row0, N);
    stage_w(Ws, wo);
    __syncthreads();
    wave_gemm<false>(As, Ws, bo, out, nullptr, row0, N);
}

// ---- fused: scores_s[j] = exp(q[row]·k[col]/4), row-sorted, bf16 q/k,
//      + segment sum over (relation, head). q-side is L1-local (sorted runs). ----
__global__ __launch_bounds__(256) void scores_exp_kernel(const unsigned short* __restrict__ q_bf,
                                                         const unsigned short* __restrict__ k_bf,
                                                         const int2* __restrict__ em,
                                                         float* __restrict__ scores_s,
                                                         float* __restrict__ s, int E) {
    __shared__ float lsum[RH];
    int tid = threadIdx.x;
    if (tid < RH) lsum[tid] = 0.f;
    __syncthreads();
    int total = E * H_;
    int stride = gridDim.x * 256;
    for (int i = blockIdx.x * 256 + tid; i < total; i += stride) {
        int j = i >> 3, h = i & 7;
        int2 m = em[j];
        int row = m.x;
        int col = m.y & 0xFFFFF, t = m.y >> 20;
        const uint4* qp = (const uint4*)(q_bf + (size_t)row * C_ + h * D_);
        const uint4* kp = (const uint4*)(k_bf + (size_t)col * C_ + h * D_);
        float acc = dot8(qp[0], kp[0]) + dot8(qp[1], kp[1]);
        float val = __expf(acc * 0.25f);    // 1/sqrt(16)
        scores_s[i] = val;
        atomicAdd(&lsum[t * H_ + h], val);
    }
    __syncthreads();
    if (tid < RH) atomicAdd(&s[tid], lsum[tid]);
}

// ---- gather: out[row] = sum over row's edges of attn * v[col]; scores contiguous ----
__global__ __launch_bounds__(64) void gather_kernel(const float* __restrict__ scores_s,
                                                    const unsigned short* __restrict__ v_bf,
                                                    const int2* __restrict__ em,
                                                    const float* __restrict__ s,
                                                    const int* __restrict__ offs,
                                                    float* __restrict__ outacc) {
    __shared__ float sinv[RH];
    int tid = threadIdx.x;
    if (tid < RH) { float sv = s[tid]; sinv[tid] = sv > 0.f ? 1.f / sv : 0.f; }
    __syncthreads();
    int row = blockIdx.x;
    int beg = offs[row], end = offs[row + 1];
    int c0 = tid * 2;            // two output channels per lane
    int h = c0 >> 4;             // head for both channels
    float ax = 0.f, ay = 0.f;
    int j = beg;
    for (; j + 1 < end; j += 2) {
        int m0 = em[j].y, m1 = em[j + 1].y;
        int col0 = m0 & 0xFFFFF, col1 = m1 & 0xFFFFF;
        float a0 = scores_s[j * H_ + h] * sinv[(m0 >> 20) * H_ + h];
        float a1 = scores_s[(j + 1) * H_ + h] * sinv[(m1 >> 20) * H_ + h];
        unsigned int p0 = *(const unsigned int*)(v_bf + (size_t)col0 * C_ + c0);
        unsigned int p1 = *(const unsigned int*)(v_bf + (size_t)col1 * C_ + c0);
        ax += bf2f((unsigned short)p0) * a0 + bf2f((unsigned short)p1) * a1;
        ay += bf2f((unsigned short)(p0 >> 16)) * a0 + bf2f((unsigned short)(p1 >> 16)) * a1;
    }
    if (j < end) {
        int m0 = em[j].y;
        int col0 = m0 & 0xFFFFF;
        float a0 = scores_s[j * H_ + h] * sinv[(m0 >> 20) * H_ + h];
        unsigned int p0 = *(const unsigned int*)(v_bf + (size_t)col0 * C_ + c0);
        ax += bf2f((unsigned short)p0) * a0;
        ay += bf2f((unsigned short)(p0 >> 16)) * a0;
    }
    *(float2*)(outacc + (size_t)row * C_ + c0) = make_float2(ax, ay);
}

extern "C" void kernel_launch(void* const* d_in, const int* in_sizes, int n_in,
                              void* d_out, int out_size, void* d_ws, size_t ws_size,
                              hipStream_t stream) {
    const float* x  = (const float*)d_in[0];
    const int*   ei = (const int*)d_in[1];
    const int*   et = (const int*)d_in[2];
    // d_in[3] = num_relations (scalar) — R_ hardcoded to 5 per problem setup
    const float* Wq = (const float*)d_in[4];
    const float* bq = (const float*)d_in[5];
    const float* Wk = (const float*)d_in[6];
    const float* bk = (const float*)d_in[7];
    const float* Wv = (const float*)d_in[8];
    const float* bv = (const float*)d_in[9];
    const float* sa = (const float*)d_in[10];
    const float* Wo = (const float*)d_in[11];
    const float* bo = (const float*)d_in[12];
    float* out = (float*)d_out;

    int N = in_sizes[0] / C_;
    int E = in_sizes[2];

    // layout (all sections 8B-aligned for int2/uint4 access):
    unsigned short* q_bf = (unsigned short*)d_ws;          // N*C bf16
    unsigned short* k_bf = q_bf + (size_t)N * C_;          // N*C bf16
    unsigned short* v_bf = k_bf + (size_t)N * C_;          // N*C bf16
    float* scores_s = (float*)(v_bf + (size_t)N * C_);     // E*8 f32
    float* s        = scores_s + (size_t)E * H_;           // RH
    float* alpha    = s + RH;                              // C (RH+C=168 f32, 8B-ok)
    int2*  em       = (int2*)(alpha + C_);                 // E int2 (row, col|type<<20)
    int*   cnt      = (int*)(em + E);                      // N ints (histogram -> cursor)
    int*   offs     = cnt + N;                             // N+1 ints
    unsigned short* w3 = (unsigned short*)(offs + N + 2);  // 3*16384 bf16 (pad to 8B)
    unsigned short* wo = w3 + 3 * 16384;                   // 16384 bf16
    int*   bsum    = (int*)(wo + 16384);                   // scan block sums
    int*   bbase   = bsum + 1024;                          // scan block bases
    float* outacc  = (float*)q_bf;   // alias: q_bf+k_bf (dead after scores) = N*C f32
    size_t need = (size_t)((char*)(bbase + 1024) - (char*)d_ws);
    if (ws_size < need) return;   // workspace too small — fail cleanly

    // ---- prep: weights to bf16, CSR build (independent of GEMMs) ----
    (void)hipMemsetAsync(cnt, 0, (size_t)N * sizeof(int), stream);
    init_kernel<<<1, 64, 0, stream>>>(sa, s, alpha);
    wprep_kernel<<<64, 256, 0, stream>>>(Wq, Wk, Wv, Wo, w3, wo);
    hist_kernel<<<(E + 255) / 256, 256, 0, stream>>>(ei, cnt, E);
    int nb = (N + 4095) / 4096;
    scan_bsum_kernel<<<nb, 1024, 0, stream>>>(cnt, bsum, N);
    scan_bbase_kernel<<<1, 64, 0, stream>>>(bsum, bbase, offs, nb, N);
    scan_local_kernel<<<nb, 1024, 0, stream>>>(cnt, offs, bbase, N);
    fill_kernel<<<(E + 255) / 256, 256, 0, stream>>>(ei, et, cnt, em, E);

    // ---- main pipeline ----
    int nrt = (N + 63) / 64;
    qkv_mfma<<<nrt * 3, 256, 0, stream>>>(x, w3, bq, bk, bv, q_bf, k_bf, v_bf, N);
    scores_exp_kernel<<<2048, 256, 0, stream>>>(q_bf, k_bf, em, scores_s, s, E);
    gather_kernel<<<N, 64, 0, stream>>>(scores_s, v_bf, em, s, offs, outacc);
    ogemm_mfma<<<nrt, 256, 0, stream>>>(outacc, alpha, wo, bo, out, N);
}